// Round 1
// baseline (1806.141 us; speedup 1.0000x reference)
//
#include <hip/hip_runtime.h>
#include <math.h>

// ---------------------------------------------------------------------------
// OmniFluids2D forward on MI355X. bf16 dataflow + MFMA everywhere GEMM-shaped.
// Y/X spectral branches merged into double-width launches. B=4, 256^2, W=64.
// R1: k_headm conv phase rewritten in fp32 FMA (bf16 dot2 path was expanding
//     to scalar unpack+FMA; drop u1 bf16 re-pack, unpack ha once per f).
// ---------------------------------------------------------------------------

typedef __attribute__((ext_vector_type(8))) short sh8;
typedef __attribute__((ext_vector_type(4))) float f4;

__device__ __forceinline__ float gelu_f(float v) {          // exact (att only)
    return 0.5f * v * (1.0f + erff(v * 0.70710678118654752f));
}
__device__ __forceinline__ float gelu_fast(float v) {       // tanh-approx
    float s = v * (1.5957691216f + 0.0713548162f * v * v);
    return v / (1.0f + __expf(-s));
}
__device__ __forceinline__ unsigned short f2bf(float x) {
    unsigned int u = __float_as_uint(x);
    u += 0x7fffu + ((u >> 16) & 1u);
    return (unsigned short)(u >> 16);
}
__device__ __forceinline__ float bf2f(unsigned short h) {
    return __uint_as_float(((unsigned int)h) << 16);
}

// ------------------------- prep: trig tables + weight packing ----------------
__global__ void k_prep(const float* __restrict__ ff_w0, const float* __restrict__ ff_w1,
                       const float* __restrict__ fa_w, const float* __restrict__ fb_w,
                       const float* __restrict__ fa_b, const float* __restrict__ fb_b,
                       const float* __restrict__ c1w, const float* __restrict__ c2w,
                       unsigned short* __restrict__ tabBf,
                       unsigned short* __restrict__ W0T, unsigned short* __restrict__ W1T,
                       unsigned short* __restrict__ Wcat, float* __restrict__ bcat,
                       unsigned int* __restrict__ c1p, unsigned int* __restrict__ c2p) {
    int idx = blockIdx.x * 256 + threadIdx.x;
    if (idx < 131072) {
        int t = idx >> 15, r = idx & 32767;
        const double PI = 3.14159265358979323846;
        const double s510 = 1.0 / sqrt(510.0);
        double v = 0.0;
        if (t == 0) {            // TAB_YF [row=2m+c][y]  (128x256)
            int row = r >> 8, y = r & 255;
            int m = row >> 1, c = row & 1;
            double ang = 2.0 * PI * (double)(m * y) / 256.0;
            v = (c == 0 ? cos(ang) : -sin(ang)) / 16.0;
        } else if (t == 1) {     // TAB_XF [row=2k+c][x]  (128x256)
            int row = r >> 8, xx = r & 255;
            int k = row >> 1, c = row & 1;
            if (c == 0) {
                v = 0.0;
                if (xx == 0)   v = s510;
                if (xx == 255) v = (k & 1) ? -s510 : s510;
            } else {
                double ang = PI * (double)(k * xx) / 255.0;
                v = -2.0 * s510 * sin(ang);
            }
        } else if (t == 2) {     // TAB_YI [y][row=2m+c]  (256x128)
            int y = r >> 7, row = r & 127;
            int m = row >> 1, c = row & 1;
            double ang = 2.0 * PI * (double)(m * y) / 256.0;
            if (c == 0) v = (m == 0 ? 1.0 : 2.0 * cos(ang)) / 16.0;
            else        v = (m == 0 ? 0.0 : -2.0 * sin(ang) / 16.0);
        } else {                 // TAB_XI [x][row=2k+c]  (256x128)
            int xx = r >> 7, row = r & 127;
            int k = row >> 1, c = row & 1;
            double ang = PI * (double)(k * xx) / 255.0;
            if (c == 0) v = s510 * (k == 0 ? 1.0 : 2.0 * cos(ang));
            else        v = (k == 0 ? 0.0 : -2.0 * s510 * sin(ang));
        }
        tabBf[idx] = f2bf((float)v);
        return;
    }
    idx -= 131072;
    if (idx < 65536) {
        int l = idx >> 14, rem = idx & 16383;
        int n = rem >> 6, k = rem & 63;
        W0T[idx] = f2bf(ff_w0[l * 16384 + k * 256 + n]);
    } else if (idx < 131072) {
        int j = idx - 65536;
        int l = j >> 14, rem = j & 16383;
        int n = rem >> 8, k = rem & 255;
        W1T[j] = f2bf(ff_w1[l * 16384 + k * 64 + n]);
    } else if (idx < 156672) {
        int j = idx - 131072;
        int f = j / 5120, r2 = j % 5120;
        int n = r2 >> 6, k = r2 & 63;
        float v = 0.0f;
        if (n < 36)      v = fa_w[f * 2304 + k * 36 + n];
        else if (n < 70) v = fb_w[f * 2176 + k * 34 + (n - 36)];
        Wcat[j] = f2bf(v);
    } else if (idx < 157072) {
        int j = idx - 156672;
        int f = j / 80, n = j % 80;
        float v = 0.0f;
        if (n < 36)      v = fa_b[f * 36 + n];
        else if (n < 70) v = fb_b[f * 34 + (n - 36)];
        bcat[j] = v;
    } else if (idx < 157552) {
        int j = idx - 157072;         // 0..479 (kept for workspace layout compat)
        int half = j >= 240;
        int r = j - half * 240;       // r = fc*6 + jj, fc = f*8+c
        int fc = r / 6, jj = r % 6;
        const float* src = half ? c2w : c1w;
        unsigned int u = (unsigned int)f2bf(src[fc * 12 + 2 * jj])
                       | ((unsigned int)f2bf(src[fc * 12 + 2 * jj + 1]) << 16);
        (half ? c2p : c1p)[r] = u;
    }
}

// ------------------------- routing attention (one block per layer) -----------
__global__ void k_att(const float* __restrict__ params,
                      const float* __restrict__ w1, const float* __restrict__ b1,
                      const float* __restrict__ w2, const float* __restrict__ b2,
                      const float* __restrict__ w3, const float* __restrict__ b3,
                      float* __restrict__ att) {
    __shared__ float A1[128], A2[128], LG[4];
    int j = threadIdx.x;   // 128 threads
    int lay = blockIdx.x;
    for (int b = 0; b < 4; ++b) {
        float s = b1[lay * 128 + j];
        for (int p = 0; p < 8; ++p) s += params[b * 8 + p] * w1[(lay * 8 + p) * 128 + j];
        A1[j] = gelu_f(s);
        __syncthreads();
        s = b2[lay * 128 + j];
        for (int q = 0; q < 128; ++q) s += A1[q] * w2[(lay * 128 + q) * 128 + j];
        A2[j] = gelu_f(s);
        __syncthreads();
        if (j < 4) {
            float tacc = b3[lay * 4 + j];
            for (int q = 0; q < 128; ++q) tacc += A2[q] * w3[(lay * 128 + q) * 4 + j];
            LG[j] = tacc * 0.1f;
        }
        __syncthreads();
        if (j == 0) {
            float mx = fmaxf(fmaxf(LG[0], LG[1]), fmaxf(LG[2], LG[3]));
            float e0 = expf(LG[0] - mx), e1 = expf(LG[1] - mx);
            float e2 = expf(LG[2] - mx), e3 = expf(LG[3] - mx);
            float inv = 1.0f / (e0 + e1 + e2 + e3);
            att[lay * 16 + b * 4 + 0] = e0 * inv;
            att[lay * 16 + b * 4 + 1] = e1 * inv;
            att[lay * 16 + b * 4 + 2] = e2 * inv;
            att[lay * 16 + b * 4 + 3] = e3 * inv;
        }
        __syncthreads();
    }
}

// ------------------------- input embedding (bf16 H only) ---------------------
__global__ __launch_bounds__(256) void k_embed(const float* __restrict__ xin,
                        const float* __restrict__ inw, const float* __restrict__ inb,
                        unsigned short* __restrict__ Hb) {
    long gid = (long)blockIdx.x * 256 + threadIdx.x;   // 0..4194303
    long px = gid >> 4;
    int c4 = (int)(gid & 15) * 4;
    int y = (int)(px & 255), xi = (int)((px >> 8) & 255);
    const float* xp = xin + px * 5;
    float v[7];
    v[0] = xp[0]; v[1] = xp[1]; v[2] = xp[2]; v[3] = xp[3]; v[4] = xp[4];
    const float STEP = 6.283185307179586f / 256.0f;
    v[5] = xi * STEP;
    v[6] = y * STEP;
    float r[4];
    #pragma unroll
    for (int c = 0; c < 4; ++c) {
        int ch = c4 + c;
        float s = inb[ch];
        #pragma unroll
        for (int p = 0; p < 7; ++p) s += v[p] * inw[p * 64 + ch];
        r[c] = gelu_fast(s);
    }
    uint2 uu;
    uu.x = (unsigned int)f2bf(r[0]) | ((unsigned int)f2bf(r[1]) << 16);
    uu.y = (unsigned int)f2bf(r[2]) | ((unsigned int)f2bf(r[3]) << 16);
    *(uint2*)(Hb + px * 64 + c4) = uu;
}

// ------------------------- W generation, both branches -----------------------
__global__ __launch_bounds__(256) void k_wgen2(
    const float* __restrict__ fwY, const float* __restrict__ fwX,
    const float* __restrict__ att,
    float* __restrict__ WRy, float* __restrict__ WIy,
    float* __restrict__ WRx, float* __restrict__ WIx) {
    int ii = blockIdx.x, b = blockIdx.y, z = blockIdx.z;
    const float* fw = z ? fwX : fwY;
    float* WRo = z ? WRx : WRy;
    float* WIo = z ? WIx : WIy;
    int tid = threadIdx.x;
    float av[4];
    av[0] = att[b * 4 + 0]; av[1] = att[b * 4 + 1];
    av[2] = att[b * 4 + 2]; av[3] = att[b * 4 + 3];
    float acc[32];
    #pragma unroll
    for (int j = 0; j < 32; ++j) acc[j] = 0.0f;
    const float* base = fw + (long)ii * 8192;
    for (int k = 0; k < 4; ++k) {
        const float* p = base + (long)k * 524288;
        float a = av[k];
        #pragma unroll
        for (int j = 0; j < 32; ++j) acc[j] += a * p[tid + j * 256];
    }
    __shared__ float ldsR[64 * 65], ldsI[64 * 65];
    #pragma unroll
    for (int j = 0; j < 32; ++j) {
        int l = tid + j * 256;                 // l over [o][m][c]
        int o = l >> 7, m = (l >> 1) & 63, c = l & 1;
        (c ? ldsI : ldsR)[o * 65 + m] = acc[j];
    }
    __syncthreads();
    long ob = (long)b * 262144 + (long)ii * 64;
    for (int w = tid; w < 4096; w += 256) {
        int m = w >> 6, o = w & 63;
        WRo[ob + (long)m * 4096 + o] = ldsR[o * 65 + m];
        WIo[ob + (long)m * 4096 + o] = ldsI[o * 65 + m];
    }
}

// ------------------------- W transpose to bf16, both branches ----------------
__global__ __launch_bounds__(256) void k_wtr2(
    const float* __restrict__ WRy, const float* __restrict__ WIy,
    const float* __restrict__ WRx, const float* __restrict__ WIx,
    unsigned short* __restrict__ WrTy, unsigned short* __restrict__ WiTy,
    unsigned short* __restrict__ WinTy,
    unsigned short* __restrict__ WrTx, unsigned short* __restrict__ WiTx,
    unsigned short* __restrict__ WinTx) {
    int z = blockIdx.y;
    const float* WR = z ? WRx : WRy;
    const float* WI = z ? WIx : WIy;
    unsigned short* WrT  = z ? WrTx  : WrTy;
    unsigned short* WiT  = z ? WiTx  : WiTy;
    unsigned short* WinT = z ? WinTx : WinTy;
    __shared__ float lR[64 * 65], lI[64 * 65];
    long base = (long)blockIdx.x * 4096;    // (b*64+m)
    int tid = threadIdx.x;
    #pragma unroll
    for (int it = 0; it < 16; ++it) {
        int l = it * 256 + tid;
        int i = l >> 6, o = l & 63;
        lR[i * 65 + o] = WR[base + l];
        lI[i * 65 + o] = WI[base + l];
    }
    __syncthreads();
    #pragma unroll
    for (int it = 0; it < 16; ++it) {
        int l = it * 256 + tid;
        int o = l >> 6, i = l & 63;
        float rr = lR[i * 65 + o], im = lI[i * 65 + o];
        WrT[base + l]  = f2bf(rr);
        WiT[base + l]  = f2bf(im);
        WinT[base + l] = f2bf(-im);
    }
}

// ------------------------- B^T staging: global rows -> lds[n][k] -------------
__device__ __forceinline__ void stage_bt(unsigned short* lds, int pitch,
    const unsigned short* src, int rowStride, int K, int tid)
{
    int pairs = K >> 1;
    int tasks = pairs * 8;
    for (int idx = tid; idx < tasks; idx += 256) {
        int p = idx & (pairs - 1);
        int cg = idx / pairs;
        const unsigned short* s0 = src + (long)(2 * p) * rowStride + cg * 8;
        sh8 r0 = *(const sh8*)s0;
        sh8 r1 = *(const sh8*)(s0 + rowStride);
        unsigned short* dbase = lds + cg * 8 * pitch + 2 * p;
        #pragma unroll
        for (int j = 0; j < 8; ++j) {
            unsigned int u = (unsigned int)(unsigned short)r0[j]
                           | ((unsigned int)(unsigned short)r1[j] << 16);
            *(unsigned int*)(dbase + j * pitch) = u;
        }
    }
}

// ------------------------- MFMA forward transform, both branches -------------
__global__ __launch_bounds__(256) void k_tf2(
    const unsigned short* __restrict__ tabY, const unsigned short* __restrict__ tabX,
    const unsigned short* __restrict__ Hb,
    unsigned short* __restrict__ Zy, unsigned short* __restrict__ Zx)
{
    __shared__ __align__(16) unsigned short ldsB[64 * 272];
    int g = blockIdx.x, br = blockIdx.y;
    int b = g >> 8, s = g & 255;
    const unsigned short* tab = br ? tabX : tabY;
    unsigned short* Zo = br ? Zx : Zy;
    long sLo = br ? 64L : 16384L;
    int rowStride = br ? 16384 : 64;
    int tid = threadIdx.x;
    const unsigned short* src = Hb + (long)b * 4194304 + (long)s * sLo;
    stage_bt(ldsB, 272, src, rowStride, 256, tid);
    __syncthreads();
    int w = tid >> 6, lane = tid & 63, q = lane >> 4, ln = lane & 15;
    f4 acc[2][4];
    #pragma unroll
    for (int mi = 0; mi < 2; ++mi)
        #pragma unroll
        for (int ni = 0; ni < 4; ++ni) acc[mi][ni] = (f4){0.f, 0.f, 0.f, 0.f};
    for (int kc = 0; kc < 256; kc += 32) {
        sh8 a[2], bf[4];
        #pragma unroll
        for (int mi = 0; mi < 2; ++mi)
            a[mi] = *(const sh8*)(tab + (w * 32 + mi * 16 + ln) * 256 + kc + q * 8);
        #pragma unroll
        for (int ni = 0; ni < 4; ++ni)
            bf[ni] = *(const sh8*)(ldsB + (ni * 16 + ln) * 272 + kc + q * 8);
        #pragma unroll
        for (int mi = 0; mi < 2; ++mi)
            #pragma unroll
            for (int ni = 0; ni < 4; ++ni)
                acc[mi][ni] = __builtin_amdgcn_mfma_f32_16x16x32_bf16(
                    a[mi], bf[ni], acc[mi][ni], 0, 0, 0);
    }
    long zB = (long)b * 2097152 + (long)s * 8192;
    #pragma unroll
    for (int mi = 0; mi < 2; ++mi)
        #pragma unroll
        for (int ni = 0; ni < 4; ++ni)
            #pragma unroll
            for (int reg = 0; reg < 4; ++reg) {
                int r = w * 32 + mi * 16 + q * 4 + reg;
                Zo[zB + r * 64 + ni * 16 + ln] = f2bf(acc[mi][ni][reg]);
            }
}

// ------------------------- MFMA complex mode-mix, both branches --------------
__global__ __launch_bounds__(256) void k_mixm2(
    unsigned short* Zy, unsigned short* Zx,
    const unsigned short* __restrict__ WrTy, const unsigned short* __restrict__ WiTy,
    const unsigned short* __restrict__ WinTy,
    const unsigned short* __restrict__ WrTx, const unsigned short* __restrict__ WiTx,
    const unsigned short* __restrict__ WinTx)
{
    int xt = blockIdx.x, g = blockIdx.y, z = blockIdx.z;
    unsigned short* Z = z ? Zx : Zy;
    const unsigned short* WrT  = z ? WrTx  : WrTy;
    const unsigned short* WiT  = z ? WiTx  : WiTy;
    const unsigned short* WinT = z ? WinTx : WinTy;
    int b = g >> 6, m = g & 63;
    int tid = threadIdx.x, w = tid >> 6, lane = tid & 63, q = lane >> 4, ln = lane & 15;
    long zB = (long)b * 2097152 + (long)m * 128;
    long wB = (long)b * 262144 + (long)m * 4096;
    int s0 = xt * 64 + w * 16;
    f4 aR[4], aI[4];
    #pragma unroll
    for (int nt = 0; nt < 4; ++nt) { aR[nt] = (f4){0.f,0.f,0.f,0.f}; aI[nt] = (f4){0.f,0.f,0.f,0.f}; }
    for (int kc = 0; kc < 64; kc += 32) {
        sh8 zr = *(const sh8*)(Z + zB + (long)(s0 + ln) * 8192 + kc + q * 8);
        sh8 zi = *(const sh8*)(Z + zB + (long)(s0 + ln) * 8192 + 64 + kc + q * 8);
        #pragma unroll
        for (int nt = 0; nt < 4; ++nt) {
            int o = nt * 16 + ln;
            sh8 wr = *(const sh8*)(WrT + wB + o * 64 + kc + q * 8);
            sh8 wi = *(const sh8*)(WiT + wB + o * 64 + kc + q * 8);
            sh8 wn = *(const sh8*)(WinT + wB + o * 64 + kc + q * 8);
            aR[nt] = __builtin_amdgcn_mfma_f32_16x16x32_bf16(zr, wr, aR[nt], 0, 0, 0);
            aR[nt] = __builtin_amdgcn_mfma_f32_16x16x32_bf16(zi, wn, aR[nt], 0, 0, 0);
            aI[nt] = __builtin_amdgcn_mfma_f32_16x16x32_bf16(zr, wi, aI[nt], 0, 0, 0);
            aI[nt] = __builtin_amdgcn_mfma_f32_16x16x32_bf16(zi, wr, aI[nt], 0, 0, 0);
        }
    }
    #pragma unroll
    for (int nt = 0; nt < 4; ++nt)
        #pragma unroll
        for (int reg = 0; reg < 4; ++reg) {
            int s = s0 + q * 4 + reg;
            long a = zB + (long)s * 8192 + nt * 16 + ln;
            Z[a]      = f2bf(aR[nt][reg]);
            Z[a + 64] = f2bf(aI[nt][reg]);
        }
}

// ------------------------- MFMA inverse transform, both branches -------------
// z=0: Ry[b][x][y][o] from Zy ; z=1: Rx[b][y][x][o] from Zx (both contiguous).
__global__ __launch_bounds__(256) void k_ti2(
    const unsigned short* __restrict__ tabY, const unsigned short* __restrict__ tabX,
    const unsigned short* __restrict__ Zy, const unsigned short* __restrict__ Zx,
    unsigned short* __restrict__ Ry, unsigned short* __restrict__ Rx)
{
    __shared__ __align__(16) unsigned short ldsB[64 * 144];
    int g = blockIdx.x, br = blockIdx.y;
    int b = g >> 8, s = g & 255;
    const unsigned short* tab = br ? tabX : tabY;
    const unsigned short* Zl  = br ? Zx : Zy;
    unsigned short* Ro = br ? Rx : Ry;
    int tid = threadIdx.x;
    const unsigned short* src = Zl + (long)b * 2097152 + (long)s * 8192;
    stage_bt(ldsB, 144, src, 64, 128, tid);
    __syncthreads();
    int w = tid >> 6, lane = tid & 63, q = lane >> 4, ln = lane & 15;
    f4 acc[4][4];
    #pragma unroll
    for (int mi = 0; mi < 4; ++mi)
        #pragma unroll
        for (int ni = 0; ni < 4; ++ni) acc[mi][ni] = (f4){0.f, 0.f, 0.f, 0.f};
    for (int kc = 0; kc < 128; kc += 32) {
        sh8 a[4], bf[4];
        #pragma unroll
        for (int mi = 0; mi < 4; ++mi)
            a[mi] = *(const sh8*)(tab + (w * 64 + mi * 16 + ln) * 128 + kc + q * 8);
        #pragma unroll
        for (int ni = 0; ni < 4; ++ni)
            bf[ni] = *(const sh8*)(ldsB + (ni * 16 + ln) * 144 + kc + q * 8);
        #pragma unroll
        for (int mi = 0; mi < 4; ++mi)
            #pragma unroll
            for (int ni = 0; ni < 4; ++ni)
                acc[mi][ni] = __builtin_amdgcn_mfma_f32_16x16x32_bf16(
                    a[mi], bf[ni], acc[mi][ni], 0, 0, 0);
    }
    long rB = (long)b * 4194304 + (long)s * 16384;
    #pragma unroll
    for (int mi = 0; mi < 4; ++mi)
        #pragma unroll
        for (int ni = 0; ni < 4; ++ni)
            #pragma unroll
            for (int reg = 0; reg < 4; ++reg) {
                int r2 = w * 64 + mi * 16 + q * 4 + reg;
                Ro[rB + (long)r2 * 64 + ni * 16 + ln] = f2bf(acc[mi][ni][reg]);
            }
}

// ------------------------- MFMA fused FeedForward + LN -----------------------
// A = bf16(Ry + Rx) built in registers; residual stream in bf16 (Hb).
__global__ __launch_bounds__(256) void k_ffm(
    const unsigned short* __restrict__ Ry, const unsigned short* __restrict__ Rx,
    const unsigned short* __restrict__ W0T, const float* __restrict__ b0,
    const unsigned short* __restrict__ W1T, const float* __restrict__ b1,
    const float* __restrict__ g1, const float* __restrict__ be1,
    unsigned short* __restrict__ Hb, int last)
{
    __shared__ __align__(16) unsigned short T[64 * 264];
    int m0 = blockIdx.x * 64;
    int tid = threadIdx.x, w = tid >> 6, lane = tid & 63, q = lane >> 4, ln = lane & 15;
    int row = m0 + w * 16 + ln;
    int bb = row >> 16, xx2 = (row >> 8) & 255, yy = row & 255;
    const unsigned short* ryp = Ry + (long)row * 64;
    const unsigned short* rxp = Rx + (long)bb * 4194304 + (long)yy * 16384 + xx2 * 64;
    // phase 1: T = relu((Ry+Rx) @ W0 + b0), rows w*16..+15, N=256
    {
        f4 acc1[16];
        #pragma unroll
        for (int nt = 0; nt < 16; ++nt) acc1[nt] = (f4){0.f, 0.f, 0.f, 0.f};
        for (int kc = 0; kc < 64; kc += 32) {
            sh8 ry = *(const sh8*)(ryp + kc + q * 8);
            sh8 rx = *(const sh8*)(rxp + kc + q * 8);
            sh8 a;
            #pragma unroll
            for (int j = 0; j < 8; ++j)
                a[j] = (short)f2bf(bf2f((unsigned short)ry[j]) + bf2f((unsigned short)rx[j]));
            #pragma unroll
            for (int nt = 0; nt < 16; ++nt) {
                sh8 bf = *(const sh8*)(W0T + (nt * 16 + ln) * 64 + kc + q * 8);
                acc1[nt] = __builtin_amdgcn_mfma_f32_16x16x32_bf16(a, bf, acc1[nt], 0, 0, 0);
            }
        }
        #pragma unroll
        for (int nt = 0; nt < 16; ++nt) {
            int n = nt * 16 + ln;
            float bias = b0[n];
            #pragma unroll
            for (int reg = 0; reg < 4; ++reg) {
                int m = w * 16 + q * 4 + reg;
                T[m * 264 + n] = f2bf(fmaxf(acc1[nt][reg] + bias, 0.0f));
            }
        }
    }
    // phase 2 (intra-wave LDS dep): t = T @ W1 + b1, then LN + residual
    f4 acc2[4];
    #pragma unroll
    for (int nt = 0; nt < 4; ++nt) acc2[nt] = (f4){0.f, 0.f, 0.f, 0.f};
    for (int kc = 0; kc < 256; kc += 32) {
        sh8 a = *(const sh8*)(T + (w * 16 + ln) * 264 + kc + q * 8);
        #pragma unroll
        for (int nt = 0; nt < 4; ++nt) {
            sh8 bf = *(const sh8*)(W1T + (nt * 16 + ln) * 256 + kc + q * 8);
            acc2[nt] = __builtin_amdgcn_mfma_f32_16x16x32_bf16(a, bf, acc2[nt], 0, 0, 0);
        }
    }
    float bia[4], gg[4], bb4[4];
    #pragma unroll
    for (int nt = 0; nt < 4; ++nt) {
        int n = nt * 16 + ln;
        bia[nt] = b1[n]; gg[nt] = g1[n]; bb4[nt] = be1[n];
    }
    #pragma unroll
    for (int reg = 0; reg < 4; ++reg) {
        float t[4];
        float s = 0.f, qs = 0.f;
        #pragma unroll
        for (int nt = 0; nt < 4; ++nt) {
            t[nt] = acc2[nt][reg] + bia[nt];
            s += t[nt]; qs += t[nt] * t[nt];
        }
        #pragma unroll
        for (int d = 1; d < 16; d <<= 1) {
            s  += __shfl_xor(s, d, 64);
            qs += __shfl_xor(qs, d, 64);
        }
        float mean = s * (1.0f / 64.0f);
        float var  = qs * (1.0f / 64.0f) - mean * mean;
        float inv  = rsqrtf(var + 1e-5f);
        int m = w * 16 + q * 4 + reg;
        long base = (long)(m0 + m) * 64;
        #pragma unroll
        for (int nt = 0; nt < 4; ++nt) {
            int n = nt * 16 + ln;
            float v = (t[nt] - mean) * inv * gg[nt] + bb4[nt];
            float hv;
            if (last) hv = gelu_fast(v);
            else      hv = bf2f(Hb[base + n]) + v;
            Hb[base + n] = f2bf(hv);
        }
    }
}

// ------------------------- output heads (MFMA ha + fp32 conv) ----------------
__global__ __launch_bounds__(256) void k_headm(
    const unsigned short* __restrict__ Hb, const float* __restrict__ x0,
    const unsigned short* __restrict__ Wcat, const float* __restrict__ bcat,
    const float* __restrict__ c1w, const float* __restrict__ c1b,
    const float* __restrict__ c2w, const float* __restrict__ c2b,
    float* __restrict__ out)
{
    __shared__ unsigned short ha[256 * 74];   // [px][j], pitch 74 (gcd(37,32)=1)
    int tid = threadIdx.x;
    long px0 = (long)blockIdx.x * 256;
    int w = tid >> 6, lane = tid & 63, q = lane >> 4, ln = lane & 15;
    // A-fragments of the ha-GEMM: load once, reuse across all 5 f
    sh8 aF[4][2];
    #pragma unroll
    for (int mi = 0; mi < 4; ++mi)
        #pragma unroll
        for (int kc = 0; kc < 2; ++kc)
            aF[mi][kc] = *(const sh8*)(Hb + (px0 + w * 64 + mi * 16 + ln) * 64
                                        + kc * 32 + q * 8);
    for (int f = 0; f < 5; ++f) {
        f4 acc[4][5];
        #pragma unroll
        for (int mi = 0; mi < 4; ++mi)
            #pragma unroll
            for (int nt = 0; nt < 5; ++nt) acc[mi][nt] = (f4){0.f, 0.f, 0.f, 0.f};
        #pragma unroll
        for (int kc = 0; kc < 2; ++kc) {
            sh8 bf[5];
            #pragma unroll
            for (int nt = 0; nt < 5; ++nt)
                bf[nt] = *(const sh8*)(Wcat + f * 5120 + (nt * 16 + ln) * 64
                                        + kc * 32 + q * 8);
            #pragma unroll
            for (int mi = 0; mi < 4; ++mi)
                #pragma unroll
                for (int nt = 0; nt < 5; ++nt)
                    acc[mi][nt] = __builtin_amdgcn_mfma_f32_16x16x32_bf16(
                        aF[mi][kc], bf[nt], acc[mi][nt], 0, 0, 0);
        }
        __syncthreads();   // previous iteration's conv reads done
        #pragma unroll
        for (int nt = 0; nt < 5; ++nt) {
            int n = nt * 16 + ln;
            if (n < 70) {
                float bias = bcat[f * 80 + n];
                #pragma unroll
                for (int mi = 0; mi < 4; ++mi)
                    #pragma unroll
                    for (int reg = 0; reg < 4; ++reg) {
                        int m = w * 64 + mi * 16 + q * 4 + reg;
                        ha[m * 74 + n] = f2bf(gelu_fast(acc[mi][nt][reg] + bias));
                    }
            }
        }
        __syncthreads();
        // conv phase: one pixel per thread, fp32 FMA on unpacked bf16 ha.
        // (bf16-pair dot path was expanding to scalar unpack+fma -> ~3x VALU)
        float hv[70];
        #pragma unroll
        for (int i = 0; i < 35; ++i) {
            unsigned int u = *(const unsigned int*)(ha + tid * 74 + 2 * i);
            hv[2 * i]     = __uint_as_float(u << 16);
            hv[2 * i + 1] = __uint_as_float(u & 0xffff0000u);
        }
        float u2[10];
        float b2v = c2b[f];
        #pragma unroll
        for (int d = 0; d < 10; ++d) u2[d] = b2v;
        #pragma unroll 1
        for (int c = 0; c < 8; ++c) {
            int fc = f * 8 + c;
            float w1r[12], w2r[12];   // uniform -> SGPRs
            #pragma unroll
            for (int j = 0; j < 12; ++j) {
                w1r[j] = c1w[fc * 12 + j];
                w2r[j] = c2w[fc * 12 + j];
            }
            float bc = c1b[fc];
            float u1[30];
            #pragma unroll
            for (int p = 0; p < 30; ++p) {
                float s = bc;
                #pragma unroll
                for (int j = 0; j < 12; ++j) s = fmaf(hv[2 * p + j], w1r[j], s);
                u1[p] = gelu_fast(s);
            }
            #pragma unroll
            for (int d = 0; d < 10; ++d) {
                float s = u2[d];
                #pragma unroll
                for (int j = 0; j < 12; ++j) s = fmaf(u1[2 * d + j], w2r[j], s);
                u2[d] = s;
            }
        }
        long px = px0 + tid;
        float xv = x0[px * 5 + f];
        #pragma unroll
        for (int d = 0; d < 10; ++d)
            out[px * 50 + f * 10 + d] = xv + u2[d] * (float)(d + 1) * 0.1f;
    }
}

// ---------------------------------------------------------------------------
extern "C" void kernel_launch(void* const* d_in, const int* in_sizes, int n_in,
                              void* d_out, int out_size, void* d_ws, size_t ws_size,
                              hipStream_t stream) {
    (void)in_sizes; (void)n_in; (void)out_size; (void)ws_size;
    const float* xin    = (const float*)d_in[0];
    const float* params = (const float*)d_in[1];
    const float* in_w   = (const float*)d_in[2];
    const float* in_b   = (const float*)d_in[3];
    const float* fnu_w1 = (const float*)d_in[4];
    const float* fnu_b1 = (const float*)d_in[5];
    const float* fnu_w2 = (const float*)d_in[6];
    const float* fnu_b2 = (const float*)d_in[7];
    const float* fnu_w3 = (const float*)d_in[8];
    const float* fnu_b3 = (const float*)d_in[9];
    const float* fw_y   = (const float*)d_in[10];
    const float* fw_x   = (const float*)d_in[11];
    const float* ff_w0  = (const float*)d_in[12];
    const float* ff_b0  = (const float*)d_in[13];
    const float* ff_w1  = (const float*)d_in[14];
    const float* ff_b1  = (const float*)d_in[15];
    const float* ln_g   = (const float*)d_in[16];
    const float* ln_b   = (const float*)d_in[17];
    const float* fa_w   = (const float*)d_in[18];
    const float* fa_b   = (const float*)d_in[19];
    const float* fb_w   = (const float*)d_in[20];
    const float* fb_b   = (const float*)d_in[21];
    const float* c1_w   = (const float*)d_in[22];
    const float* c1_b   = (const float*)d_in[23];
    const float* c2_w   = (const float*)d_in[24];
    const float* c2_b   = (const float*)d_in[25];
    float* out = (float*)d_out;
    float* ws  = (float*)d_ws;

    // workspace (float offsets), total ~41.0M floats (~164 MB)
    unsigned short* tabBf = (unsigned short*)(ws + 0);        // 131072 sh
    unsigned short* tabYF = tabBf;
    unsigned short* tabXF = tabBf + 32768;
    unsigned short* tabYI = tabBf + 65536;
    unsigned short* tabXI = tabBf + 98304;
    unsigned short* W0T   = (unsigned short*)(ws + 65536);    // 65536 sh
    unsigned short* W1T   = (unsigned short*)(ws + 98304);    // 65536 sh
    unsigned short* Wcat  = (unsigned short*)(ws + 131072);   // 25600 sh
    float* bcat = ws + 143872;                                 // 400
    float* att  = ws + 144272;                                 // 64
    unsigned int* c1p = (unsigned int*)(ws + 144336);          // 240 (unused by heads now)
    unsigned int* c2p = (unsigned int*)(ws + 144576);          // 240 (unused by heads now)
    unsigned short* Hbf = (unsigned short*)(ws + 144816);      // 16.8M sh
    float* WRy = ws + 8533424;   // 1048576 each
    float* WIy = ws + 9582000;
    float* WRx = ws + 10630576;
    float* WIx = ws + 11679152;
    unsigned short* WrTy  = (unsigned short*)(ws + 12727728);  // 1M sh each
    unsigned short* WiTy  = (unsigned short*)(ws + 13252016);
    unsigned short* WinTy = (unsigned short*)(ws + 13776304);
    unsigned short* WrTx  = (unsigned short*)(ws + 14300592);
    unsigned short* WiTx  = (unsigned short*)(ws + 14824880);
    unsigned short* WinTx = (unsigned short*)(ws + 15349168);
    unsigned short* Zy    = (unsigned short*)(ws + 15873456);  // 8.4M sh
    unsigned short* Zx    = (unsigned short*)(ws + 20067760);  // 8.4M sh
    unsigned short* Ry    = (unsigned short*)(ws + 24262064);  // 16.8M sh
    unsigned short* Rx    = (unsigned short*)(ws + 32650672);  // 16.8M sh

    k_prep<<<1128, 256, 0, stream>>>(ff_w0, ff_w1, fa_w, fb_w, fa_b, fb_b,
                                     c1_w, c2_w, tabBf, W0T, W1T, Wcat, bcat, c1p, c2p);
    k_att<<<4, 128, 0, stream>>>(params, fnu_w1, fnu_b1, fnu_w2, fnu_b2, fnu_w3, fnu_b3, att);
    k_embed<<<16384, 256, 0, stream>>>(xin, in_w, in_b, Hbf);

    for (int lay = 0; lay < 4; ++lay) {
        const float* attL = att + lay * 16;
        k_wgen2<<<dim3(64, 4, 2), 256, 0, stream>>>(
            fw_y + (long)lay * 2097152, fw_x + (long)lay * 2097152, attL,
            WRy, WIy, WRx, WIx);
        k_wtr2<<<dim3(256, 2), 256, 0, stream>>>(
            WRy, WIy, WRx, WIx, WrTy, WiTy, WinTy, WrTx, WiTx, WinTx);
        k_tf2<<<dim3(1024, 2), 256, 0, stream>>>(tabYF, tabXF, Hbf, Zy, Zx);
        k_mixm2<<<dim3(4, 256, 2), 256, 0, stream>>>(
            Zy, Zx, WrTy, WiTy, WinTy, WrTx, WiTx, WinTx);
        k_ti2<<<dim3(1024, 2), 256, 0, stream>>>(tabYI, tabXI, Zy, Zx, Ry, Rx);
        k_ffm<<<4096, 256, 0, stream>>>(
            Ry, Rx, W0T + lay * 16384, ff_b0 + lay * 256,
            W1T + lay * 16384, ff_b1 + lay * 64,
            ln_g + lay * 64, ln_b + lay * 64,
            Hbf, (lay == 3) ? 1 : 0);
    }
    k_headm<<<1024, 256, 0, stream>>>(Hbf, xin, Wcat, bcat,
                                      c1_w, c1_b, c2_w, c2_b, out);
}

// Round 3
// 1694.487 us; speedup vs baseline: 1.0659x; 1.0659x over previous
//
#include <hip/hip_runtime.h>
#include <math.h>

// ---------------------------------------------------------------------------
// OmniFluids2D forward on MI355X. bf16 dataflow + MFMA everywhere GEMM-shaped.
// Y/X spectral branches merged into double-width launches. B=4, 256^2, W=64.
// R2/R3: gelu_fast uses v_rcp (div was expanding to ~12-instr sequence);
//     k_headm conv: no u1[] live array (immediate conv2 scatter), hv window
//     processed in two 40-float halves -> ~70 live VGPRs, no spills.
//     R3 = R2 resubmit (container infra failure), rcp builtin guarded.
// ---------------------------------------------------------------------------

typedef __attribute__((ext_vector_type(8))) short sh8;
typedef __attribute__((ext_vector_type(4))) float f4;

__device__ __forceinline__ float fast_rcp(float x) {
#if defined(__has_builtin)
#if __has_builtin(__builtin_amdgcn_rcpf)
    return __builtin_amdgcn_rcpf(x);
#else
    return 1.0f / x;
#endif
#else
    return 1.0f / x;
#endif
}

__device__ __forceinline__ float gelu_f(float v) {          // exact (att only)
    return 0.5f * v * (1.0f + erff(v * 0.70710678118654752f));
}
__device__ __forceinline__ float gelu_fast(float v) {       // tanh-approx, rcp
    float s = v * (1.5957691216f + 0.0713548162f * v * v);
    float e = __expf(-s);
    return v * fast_rcp(1.0f + e);
}
__device__ __forceinline__ unsigned short f2bf(float x) {
    unsigned int u = __float_as_uint(x);
    u += 0x7fffu + ((u >> 16) & 1u);
    return (unsigned short)(u >> 16);
}
__device__ __forceinline__ float bf2f(unsigned short h) {
    return __uint_as_float(((unsigned int)h) << 16);
}

// ------------------------- prep: trig tables + weight packing ----------------
__global__ void k_prep(const float* __restrict__ ff_w0, const float* __restrict__ ff_w1,
                       const float* __restrict__ fa_w, const float* __restrict__ fb_w,
                       const float* __restrict__ fa_b, const float* __restrict__ fb_b,
                       const float* __restrict__ c1w, const float* __restrict__ c2w,
                       unsigned short* __restrict__ tabBf,
                       unsigned short* __restrict__ W0T, unsigned short* __restrict__ W1T,
                       unsigned short* __restrict__ Wcat, float* __restrict__ bcat,
                       unsigned int* __restrict__ c1p, unsigned int* __restrict__ c2p) {
    int idx = blockIdx.x * 256 + threadIdx.x;
    if (idx < 131072) {
        int t = idx >> 15, r = idx & 32767;
        const double PI = 3.14159265358979323846;
        const double s510 = 1.0 / sqrt(510.0);
        double v = 0.0;
        if (t == 0) {            // TAB_YF [row=2m+c][y]  (128x256)
            int row = r >> 8, y = r & 255;
            int m = row >> 1, c = row & 1;
            double ang = 2.0 * PI * (double)(m * y) / 256.0;
            v = (c == 0 ? cos(ang) : -sin(ang)) / 16.0;
        } else if (t == 1) {     // TAB_XF [row=2k+c][x]  (128x256)
            int row = r >> 8, xx = r & 255;
            int k = row >> 1, c = row & 1;
            if (c == 0) {
                v = 0.0;
                if (xx == 0)   v = s510;
                if (xx == 255) v = (k & 1) ? -s510 : s510;
            } else {
                double ang = PI * (double)(k * xx) / 255.0;
                v = -2.0 * s510 * sin(ang);
            }
        } else if (t == 2) {     // TAB_YI [y][row=2m+c]  (256x128)
            int y = r >> 7, row = r & 127;
            int m = row >> 1, c = row & 1;
            double ang = 2.0 * PI * (double)(m * y) / 256.0;
            if (c == 0) v = (m == 0 ? 1.0 : 2.0 * cos(ang)) / 16.0;
            else        v = (m == 0 ? 0.0 : -2.0 * sin(ang) / 16.0);
        } else {                 // TAB_XI [x][row=2k+c]  (256x128)
            int xx = r >> 7, row = r & 127;
            int k = row >> 1, c = row & 1;
            double ang = PI * (double)(k * xx) / 255.0;
            if (c == 0) v = s510 * (k == 0 ? 1.0 : 2.0 * cos(ang));
            else        v = (k == 0 ? 0.0 : -2.0 * s510 * sin(ang));
        }
        tabBf[idx] = f2bf((float)v);
        return;
    }
    idx -= 131072;
    if (idx < 65536) {
        int l = idx >> 14, rem = idx & 16383;
        int n = rem >> 6, k = rem & 63;
        W0T[idx] = f2bf(ff_w0[l * 16384 + k * 256 + n]);
    } else if (idx < 131072) {
        int j = idx - 65536;
        int l = j >> 14, rem = j & 16383;
        int n = rem >> 8, k = rem & 255;
        W1T[j] = f2bf(ff_w1[l * 16384 + k * 64 + n]);
    } else if (idx < 156672) {
        int j = idx - 131072;
        int f = j / 5120, r2 = j % 5120;
        int n = r2 >> 6, k = r2 & 63;
        float v = 0.0f;
        if (n < 36)      v = fa_w[f * 2304 + k * 36 + n];
        else if (n < 70) v = fb_w[f * 2176 + k * 34 + (n - 36)];
        Wcat[j] = f2bf(v);
    } else if (idx < 157072) {
        int j = idx - 156672;
        int f = j / 80, n = j % 80;
        float v = 0.0f;
        if (n < 36)      v = fa_b[f * 36 + n];
        else if (n < 70) v = fb_b[f * 34 + (n - 36)];
        bcat[j] = v;
    } else if (idx < 157552) {
        int j = idx - 157072;         // 0..479 (kept for workspace layout compat)
        int half = j >= 240;
        int r = j - half * 240;       // r = fc*6 + jj, fc = f*8+c
        int fc = r / 6, jj = r % 6;
        const float* src = half ? c2w : c1w;
        unsigned int u = (unsigned int)f2bf(src[fc * 12 + 2 * jj])
                       | ((unsigned int)f2bf(src[fc * 12 + 2 * jj + 1]) << 16);
        (half ? c2p : c1p)[r] = u;
    }
}

// ------------------------- routing attention (one block per layer) -----------
__global__ void k_att(const float* __restrict__ params,
                      const float* __restrict__ w1, const float* __restrict__ b1,
                      const float* __restrict__ w2, const float* __restrict__ b2,
                      const float* __restrict__ w3, const float* __restrict__ b3,
                      float* __restrict__ att) {
    __shared__ float A1[128], A2[128], LG[4];
    int j = threadIdx.x;   // 128 threads
    int lay = blockIdx.x;
    for (int b = 0; b < 4; ++b) {
        float s = b1[lay * 128 + j];
        for (int p = 0; p < 8; ++p) s += params[b * 8 + p] * w1[(lay * 8 + p) * 128 + j];
        A1[j] = gelu_f(s);
        __syncthreads();
        s = b2[lay * 128 + j];
        for (int q = 0; q < 128; ++q) s += A1[q] * w2[(lay * 128 + q) * 128 + j];
        A2[j] = gelu_f(s);
        __syncthreads();
        if (j < 4) {
            float tacc = b3[lay * 4 + j];
            for (int q = 0; q < 128; ++q) tacc += A2[q] * w3[(lay * 128 + q) * 4 + j];
            LG[j] = tacc * 0.1f;
        }
        __syncthreads();
        if (j == 0) {
            float mx = fmaxf(fmaxf(LG[0], LG[1]), fmaxf(LG[2], LG[3]));
            float e0 = expf(LG[0] - mx), e1 = expf(LG[1] - mx);
            float e2 = expf(LG[2] - mx), e3 = expf(LG[3] - mx);
            float inv = 1.0f / (e0 + e1 + e2 + e3);
            att[lay * 16 + b * 4 + 0] = e0 * inv;
            att[lay * 16 + b * 4 + 1] = e1 * inv;
            att[lay * 16 + b * 4 + 2] = e2 * inv;
            att[lay * 16 + b * 4 + 3] = e3 * inv;
        }
        __syncthreads();
    }
}

// ------------------------- input embedding (bf16 H only) ---------------------
__global__ __launch_bounds__(256) void k_embed(const float* __restrict__ xin,
                        const float* __restrict__ inw, const float* __restrict__ inb,
                        unsigned short* __restrict__ Hb) {
    long gid = (long)blockIdx.x * 256 + threadIdx.x;   // 0..4194303
    long px = gid >> 4;
    int c4 = (int)(gid & 15) * 4;
    int y = (int)(px & 255), xi = (int)((px >> 8) & 255);
    const float* xp = xin + px * 5;
    float v[7];
    v[0] = xp[0]; v[1] = xp[1]; v[2] = xp[2]; v[3] = xp[3]; v[4] = xp[4];
    const float STEP = 6.283185307179586f / 256.0f;
    v[5] = xi * STEP;
    v[6] = y * STEP;
    float r[4];
    #pragma unroll
    for (int c = 0; c < 4; ++c) {
        int ch = c4 + c;
        float s = inb[ch];
        #pragma unroll
        for (int p = 0; p < 7; ++p) s += v[p] * inw[p * 64 + ch];
        r[c] = gelu_fast(s);
    }
    uint2 uu;
    uu.x = (unsigned int)f2bf(r[0]) | ((unsigned int)f2bf(r[1]) << 16);
    uu.y = (unsigned int)f2bf(r[2]) | ((unsigned int)f2bf(r[3]) << 16);
    *(uint2*)(Hb + px * 64 + c4) = uu;
}

// ------------------------- W generation, both branches -----------------------
__global__ __launch_bounds__(256) void k_wgen2(
    const float* __restrict__ fwY, const float* __restrict__ fwX,
    const float* __restrict__ att,
    float* __restrict__ WRy, float* __restrict__ WIy,
    float* __restrict__ WRx, float* __restrict__ WIx) {
    int ii = blockIdx.x, b = blockIdx.y, z = blockIdx.z;
    const float* fw = z ? fwX : fwY;
    float* WRo = z ? WRx : WRy;
    float* WIo = z ? WIx : WIy;
    int tid = threadIdx.x;
    float av[4];
    av[0] = att[b * 4 + 0]; av[1] = att[b * 4 + 1];
    av[2] = att[b * 4 + 2]; av[3] = att[b * 4 + 3];
    float acc[32];
    #pragma unroll
    for (int j = 0; j < 32; ++j) acc[j] = 0.0f;
    const float* base = fw + (long)ii * 8192;
    for (int k = 0; k < 4; ++k) {
        const float* p = base + (long)k * 524288;
        float a = av[k];
        #pragma unroll
        for (int j = 0; j < 32; ++j) acc[j] += a * p[tid + j * 256];
    }
    __shared__ float ldsR[64 * 65], ldsI[64 * 65];
    #pragma unroll
    for (int j = 0; j < 32; ++j) {
        int l = tid + j * 256;                 // l over [o][m][c]
        int o = l >> 7, m = (l >> 1) & 63, c = l & 1;
        (c ? ldsI : ldsR)[o * 65 + m] = acc[j];
    }
    __syncthreads();
    long ob = (long)b * 262144 + (long)ii * 64;
    for (int w = tid; w < 4096; w += 256) {
        int m = w >> 6, o = w & 63;
        WRo[ob + (long)m * 4096 + o] = ldsR[o * 65 + m];
        WIo[ob + (long)m * 4096 + o] = ldsI[o * 65 + m];
    }
}

// ------------------------- W transpose to bf16, both branches ----------------
__global__ __launch_bounds__(256) void k_wtr2(
    const float* __restrict__ WRy, const float* __restrict__ WIy,
    const float* __restrict__ WRx, const float* __restrict__ WIx,
    unsigned short* __restrict__ WrTy, unsigned short* __restrict__ WiTy,
    unsigned short* __restrict__ WinTy,
    unsigned short* __restrict__ WrTx, unsigned short* __restrict__ WiTx,
    unsigned short* __restrict__ WinTx) {
    int z = blockIdx.y;
    const float* WR = z ? WRx : WRy;
    const float* WI = z ? WIx : WIy;
    unsigned short* WrT  = z ? WrTx  : WrTy;
    unsigned short* WiT  = z ? WiTx  : WiTy;
    unsigned short* WinT = z ? WinTx : WinTy;
    __shared__ float lR[64 * 65], lI[64 * 65];
    long base = (long)blockIdx.x * 4096;    // (b*64+m)
    int tid = threadIdx.x;
    #pragma unroll
    for (int it = 0; it < 16; ++it) {
        int l = it * 256 + tid;
        int i = l >> 6, o = l & 63;
        lR[i * 65 + o] = WR[base + l];
        lI[i * 65 + o] = WI[base + l];
    }
    __syncthreads();
    #pragma unroll
    for (int it = 0; it < 16; ++it) {
        int l = it * 256 + tid;
        int o = l >> 6, i = l & 63;
        float rr = lR[i * 65 + o], im = lI[i * 65 + o];
        WrT[base + l]  = f2bf(rr);
        WiT[base + l]  = f2bf(im);
        WinT[base + l] = f2bf(-im);
    }
}

// ------------------------- B^T staging: global rows -> lds[n][k] -------------
__device__ __forceinline__ void stage_bt(unsigned short* lds, int pitch,
    const unsigned short* src, int rowStride, int K, int tid)
{
    int pairs = K >> 1;
    int tasks = pairs * 8;
    for (int idx = tid; idx < tasks; idx += 256) {
        int p = idx & (pairs - 1);
        int cg = idx / pairs;
        const unsigned short* s0 = src + (long)(2 * p) * rowStride + cg * 8;
        sh8 r0 = *(const sh8*)s0;
        sh8 r1 = *(const sh8*)(s0 + rowStride);
        unsigned short* dbase = lds + cg * 8 * pitch + 2 * p;
        #pragma unroll
        for (int j = 0; j < 8; ++j) {
            unsigned int u = (unsigned int)(unsigned short)r0[j]
                           | ((unsigned int)(unsigned short)r1[j] << 16);
            *(unsigned int*)(dbase + j * pitch) = u;
        }
    }
}

// ------------------------- MFMA forward transform, both branches -------------
__global__ __launch_bounds__(256) void k_tf2(
    const unsigned short* __restrict__ tabY, const unsigned short* __restrict__ tabX,
    const unsigned short* __restrict__ Hb,
    unsigned short* __restrict__ Zy, unsigned short* __restrict__ Zx)
{
    __shared__ __align__(16) unsigned short ldsB[64 * 272];
    int g = blockIdx.x, br = blockIdx.y;
    int b = g >> 8, s = g & 255;
    const unsigned short* tab = br ? tabX : tabY;
    unsigned short* Zo = br ? Zx : Zy;
    long sLo = br ? 64L : 16384L;
    int rowStride = br ? 16384 : 64;
    int tid = threadIdx.x;
    const unsigned short* src = Hb + (long)b * 4194304 + (long)s * sLo;
    stage_bt(ldsB, 272, src, rowStride, 256, tid);
    __syncthreads();
    int w = tid >> 6, lane = tid & 63, q = lane >> 4, ln = lane & 15;
    f4 acc[2][4];
    #pragma unroll
    for (int mi = 0; mi < 2; ++mi)
        #pragma unroll
        for (int ni = 0; ni < 4; ++ni) acc[mi][ni] = (f4){0.f, 0.f, 0.f, 0.f};
    for (int kc = 0; kc < 256; kc += 32) {
        sh8 a[2], bf[4];
        #pragma unroll
        for (int mi = 0; mi < 2; ++mi)
            a[mi] = *(const sh8*)(tab + (w * 32 + mi * 16 + ln) * 256 + kc + q * 8);
        #pragma unroll
        for (int ni = 0; ni < 4; ++ni)
            bf[ni] = *(const sh8*)(ldsB + (ni * 16 + ln) * 272 + kc + q * 8);
        #pragma unroll
        for (int mi = 0; mi < 2; ++mi)
            #pragma unroll
            for (int ni = 0; ni < 4; ++ni)
                acc[mi][ni] = __builtin_amdgcn_mfma_f32_16x16x32_bf16(
                    a[mi], bf[ni], acc[mi][ni], 0, 0, 0);
    }
    long zB = (long)b * 2097152 + (long)s * 8192;
    #pragma unroll
    for (int mi = 0; mi < 2; ++mi)
        #pragma unroll
        for (int ni = 0; ni < 4; ++ni)
            #pragma unroll
            for (int reg = 0; reg < 4; ++reg) {
                int r = w * 32 + mi * 16 + q * 4 + reg;
                Zo[zB + r * 64 + ni * 16 + ln] = f2bf(acc[mi][ni][reg]);
            }
}

// ------------------------- MFMA complex mode-mix, both branches --------------
__global__ __launch_bounds__(256) void k_mixm2(
    unsigned short* Zy, unsigned short* Zx,
    const unsigned short* __restrict__ WrTy, const unsigned short* __restrict__ WiTy,
    const unsigned short* __restrict__ WinTy,
    const unsigned short* __restrict__ WrTx, const unsigned short* __restrict__ WiTx,
    const unsigned short* __restrict__ WinTx)
{
    int xt = blockIdx.x, g = blockIdx.y, z = blockIdx.z;
    unsigned short* Z = z ? Zx : Zy;
    const unsigned short* WrT  = z ? WrTx  : WrTy;
    const unsigned short* WiT  = z ? WiTx  : WiTy;
    const unsigned short* WinT = z ? WinTx : WinTy;
    int b = g >> 6, m = g & 63;
    int tid = threadIdx.x, w = tid >> 6, lane = tid & 63, q = lane >> 4, ln = lane & 15;
    long zB = (long)b * 2097152 + (long)m * 128;
    long wB = (long)b * 262144 + (long)m * 4096;
    int s0 = xt * 64 + w * 16;
    f4 aR[4], aI[4];
    #pragma unroll
    for (int nt = 0; nt < 4; ++nt) { aR[nt] = (f4){0.f,0.f,0.f,0.f}; aI[nt] = (f4){0.f,0.f,0.f,0.f}; }
    for (int kc = 0; kc < 64; kc += 32) {
        sh8 zr = *(const sh8*)(Z + zB + (long)(s0 + ln) * 8192 + kc + q * 8);
        sh8 zi = *(const sh8*)(Z + zB + (long)(s0 + ln) * 8192 + 64 + kc + q * 8);
        #pragma unroll
        for (int nt = 0; nt < 4; ++nt) {
            int o = nt * 16 + ln;
            sh8 wr = *(const sh8*)(WrT + wB + o * 64 + kc + q * 8);
            sh8 wi = *(const sh8*)(WiT + wB + o * 64 + kc + q * 8);
            sh8 wn = *(const sh8*)(WinT + wB + o * 64 + kc + q * 8);
            aR[nt] = __builtin_amdgcn_mfma_f32_16x16x32_bf16(zr, wr, aR[nt], 0, 0, 0);
            aR[nt] = __builtin_amdgcn_mfma_f32_16x16x32_bf16(zi, wn, aR[nt], 0, 0, 0);
            aI[nt] = __builtin_amdgcn_mfma_f32_16x16x32_bf16(zr, wi, aI[nt], 0, 0, 0);
            aI[nt] = __builtin_amdgcn_mfma_f32_16x16x32_bf16(zi, wr, aI[nt], 0, 0, 0);
        }
    }
    #pragma unroll
    for (int nt = 0; nt < 4; ++nt)
        #pragma unroll
        for (int reg = 0; reg < 4; ++reg) {
            int s = s0 + q * 4 + reg;
            long a = zB + (long)s * 8192 + nt * 16 + ln;
            Z[a]      = f2bf(aR[nt][reg]);
            Z[a + 64] = f2bf(aI[nt][reg]);
        }
}

// ------------------------- MFMA inverse transform, both branches -------------
// z=0: Ry[b][x][y][o] from Zy ; z=1: Rx[b][y][x][o] from Zx (both contiguous).
__global__ __launch_bounds__(256) void k_ti2(
    const unsigned short* __restrict__ tabY, const unsigned short* __restrict__ tabX,
    const unsigned short* __restrict__ Zy, const unsigned short* __restrict__ Zx,
    unsigned short* __restrict__ Ry, unsigned short* __restrict__ Rx)
{
    __shared__ __align__(16) unsigned short ldsB[64 * 144];
    int g = blockIdx.x, br = blockIdx.y;
    int b = g >> 8, s = g & 255;
    const unsigned short* tab = br ? tabX : tabY;
    const unsigned short* Zl  = br ? Zx : Zy;
    unsigned short* Ro = br ? Rx : Ry;
    int tid = threadIdx.x;
    const unsigned short* src = Zl + (long)b * 2097152 + (long)s * 8192;
    stage_bt(ldsB, 144, src, 64, 128, tid);
    __syncthreads();
    int w = tid >> 6, lane = tid & 63, q = lane >> 4, ln = lane & 15;
    f4 acc[4][4];
    #pragma unroll
    for (int mi = 0; mi < 4; ++mi)
        #pragma unroll
        for (int ni = 0; ni < 4; ++ni) acc[mi][ni] = (f4){0.f, 0.f, 0.f, 0.f};
    for (int kc = 0; kc < 128; kc += 32) {
        sh8 a[4], bf[4];
        #pragma unroll
        for (int mi = 0; mi < 4; ++mi)
            a[mi] = *(const sh8*)(tab + (w * 64 + mi * 16 + ln) * 128 + kc + q * 8);
        #pragma unroll
        for (int ni = 0; ni < 4; ++ni)
            bf[ni] = *(const sh8*)(ldsB + (ni * 16 + ln) * 144 + kc + q * 8);
        #pragma unroll
        for (int mi = 0; mi < 4; ++mi)
            #pragma unroll
            for (int ni = 0; ni < 4; ++ni)
                acc[mi][ni] = __builtin_amdgcn_mfma_f32_16x16x32_bf16(
                    a[mi], bf[ni], acc[mi][ni], 0, 0, 0);
    }
    long rB = (long)b * 4194304 + (long)s * 16384;
    #pragma unroll
    for (int mi = 0; mi < 4; ++mi)
        #pragma unroll
        for (int ni = 0; ni < 4; ++ni)
            #pragma unroll
            for (int reg = 0; reg < 4; ++reg) {
                int r2 = w * 64 + mi * 16 + q * 4 + reg;
                Ro[rB + (long)r2 * 64 + ni * 16 + ln] = f2bf(acc[mi][ni][reg]);
            }
}

// ------------------------- MFMA fused FeedForward + LN -----------------------
// A = bf16(Ry + Rx) built in registers; residual stream in bf16 (Hb).
__global__ __launch_bounds__(256) void k_ffm(
    const unsigned short* __restrict__ Ry, const unsigned short* __restrict__ Rx,
    const unsigned short* __restrict__ W0T, const float* __restrict__ b0,
    const unsigned short* __restrict__ W1T, const float* __restrict__ b1,
    const float* __restrict__ g1, const float* __restrict__ be1,
    unsigned short* __restrict__ Hb, int last)
{
    __shared__ __align__(16) unsigned short T[64 * 264];
    int m0 = blockIdx.x * 64;
    int tid = threadIdx.x, w = tid >> 6, lane = tid & 63, q = lane >> 4, ln = lane & 15;
    int row = m0 + w * 16 + ln;
    int bb = row >> 16, xx2 = (row >> 8) & 255, yy = row & 255;
    const unsigned short* ryp = Ry + (long)row * 64;
    const unsigned short* rxp = Rx + (long)bb * 4194304 + (long)yy * 16384 + xx2 * 64;
    // phase 1: T = relu((Ry+Rx) @ W0 + b0), rows w*16..+15, N=256
    {
        f4 acc1[16];
        #pragma unroll
        for (int nt = 0; nt < 16; ++nt) acc1[nt] = (f4){0.f, 0.f, 0.f, 0.f};
        for (int kc = 0; kc < 64; kc += 32) {
            sh8 ry = *(const sh8*)(ryp + kc + q * 8);
            sh8 rx = *(const sh8*)(rxp + kc + q * 8);
            sh8 a;
            #pragma unroll
            for (int j = 0; j < 8; ++j)
                a[j] = (short)f2bf(bf2f((unsigned short)ry[j]) + bf2f((unsigned short)rx[j]));
            #pragma unroll
            for (int nt = 0; nt < 16; ++nt) {
                sh8 bf = *(const sh8*)(W0T + (nt * 16 + ln) * 64 + kc + q * 8);
                acc1[nt] = __builtin_amdgcn_mfma_f32_16x16x32_bf16(a, bf, acc1[nt], 0, 0, 0);
            }
        }
        #pragma unroll
        for (int nt = 0; nt < 16; ++nt) {
            int n = nt * 16 + ln;
            float bias = b0[n];
            #pragma unroll
            for (int reg = 0; reg < 4; ++reg) {
                int m = w * 16 + q * 4 + reg;
                T[m * 264 + n] = f2bf(fmaxf(acc1[nt][reg] + bias, 0.0f));
            }
        }
    }
    // phase 2 (intra-wave LDS dep): t = T @ W1 + b1, then LN + residual
    f4 acc2[4];
    #pragma unroll
    for (int nt = 0; nt < 4; ++nt) acc2[nt] = (f4){0.f, 0.f, 0.f, 0.f};
    for (int kc = 0; kc < 256; kc += 32) {
        sh8 a = *(const sh8*)(T + (w * 16 + ln) * 264 + kc + q * 8);
        #pragma unroll
        for (int nt = 0; nt < 4; ++nt) {
            sh8 bf = *(const sh8*)(W1T + (nt * 16 + ln) * 256 + kc + q * 8);
            acc2[nt] = __builtin_amdgcn_mfma_f32_16x16x32_bf16(a, bf, acc2[nt], 0, 0, 0);
        }
    }
    float bia[4], gg[4], bb4[4];
    #pragma unroll
    for (int nt = 0; nt < 4; ++nt) {
        int n = nt * 16 + ln;
        bia[nt] = b1[n]; gg[nt] = g1[n]; bb4[nt] = be1[n];
    }
    #pragma unroll
    for (int reg = 0; reg < 4; ++reg) {
        float t[4];
        float s = 0.f, qs = 0.f;
        #pragma unroll
        for (int nt = 0; nt < 4; ++nt) {
            t[nt] = acc2[nt][reg] + bia[nt];
            s += t[nt]; qs += t[nt] * t[nt];
        }
        #pragma unroll
        for (int d = 1; d < 16; d <<= 1) {
            s  += __shfl_xor(s, d, 64);
            qs += __shfl_xor(qs, d, 64);
        }
        float mean = s * (1.0f / 64.0f);
        float var  = qs * (1.0f / 64.0f) - mean * mean;
        float inv  = rsqrtf(var + 1e-5f);
        int m = w * 16 + q * 4 + reg;
        long base = (long)(m0 + m) * 64;
        #pragma unroll
        for (int nt = 0; nt < 4; ++nt) {
            int n = nt * 16 + ln;
            float v = (t[nt] - mean) * inv * gg[nt] + bb4[nt];
            float hv;
            if (last) hv = gelu_fast(v);
            else      hv = bf2f(Hb[base + n]) + v;
            Hb[base + n] = f2bf(hv);
        }
    }
}

// ------------------------- output heads (MFMA ha + fp32 conv) ----------------
__global__ __launch_bounds__(256) void k_headm(
    const unsigned short* __restrict__ Hb, const float* __restrict__ x0,
    const unsigned short* __restrict__ Wcat, const float* __restrict__ bcat,
    const float* __restrict__ c1w, const float* __restrict__ c1b,
    const float* __restrict__ c2w, const float* __restrict__ c2b,
    float* __restrict__ out)
{
    __shared__ unsigned short ha[256 * 74];   // [px][j], pitch 74 (gcd(37,32)=1)
    int tid = threadIdx.x;
    long px0 = (long)blockIdx.x * 256;
    int w = tid >> 6, lane = tid & 63, q = lane >> 4, ln = lane & 15;
    // A-fragments of the ha-GEMM: load once, reuse across all 5 f
    sh8 aF[4][2];
    #pragma unroll
    for (int mi = 0; mi < 4; ++mi)
        #pragma unroll
        for (int kc = 0; kc < 2; ++kc)
            aF[mi][kc] = *(const sh8*)(Hb + (px0 + w * 64 + mi * 16 + ln) * 64
                                        + kc * 32 + q * 8);
    for (int f = 0; f < 5; ++f) {
        f4 acc[4][5];
        #pragma unroll
        for (int mi = 0; mi < 4; ++mi)
            #pragma unroll
            for (int nt = 0; nt < 5; ++nt) acc[mi][nt] = (f4){0.f, 0.f, 0.f, 0.f};
        #pragma unroll
        for (int kc = 0; kc < 2; ++kc) {
            sh8 bf[5];
            #pragma unroll
            for (int nt = 0; nt < 5; ++nt)
                bf[nt] = *(const sh8*)(Wcat + f * 5120 + (nt * 16 + ln) * 64
                                        + kc * 32 + q * 8);
            #pragma unroll
            for (int mi = 0; mi < 4; ++mi)
                #pragma unroll
                for (int nt = 0; nt < 5; ++nt)
                    acc[mi][nt] = __builtin_amdgcn_mfma_f32_16x16x32_bf16(
                        aF[mi][kc], bf[nt], acc[mi][nt], 0, 0, 0);
        }
        __syncthreads();   // previous iteration's conv reads done
        #pragma unroll
        for (int nt = 0; nt < 5; ++nt) {
            int n = nt * 16 + ln;
            if (n < 70) {
                float bias = bcat[f * 80 + n];
                #pragma unroll
                for (int mi = 0; mi < 4; ++mi)
                    #pragma unroll
                    for (int reg = 0; reg < 4; ++reg) {
                        int m = w * 64 + mi * 16 + q * 4 + reg;
                        ha[m * 74 + n] = f2bf(gelu_fast(acc[mi][nt][reg] + bias));
                    }
            }
        }
        __syncthreads();
        // conv phase: one pixel per thread, fp32 FMA.
        // - conv2 scattered immediately after each gelu: no u1[30] live array
        // - hv window processed in two 40-float halves: peak live ~70 regs
        float u2[10];
        float b2v = c2b[f];
        #pragma unroll
        for (int d = 0; d < 10; ++d) u2[d] = b2v;
        #pragma unroll
        for (int h = 0; h < 2; ++h) {
            float hw[40];   // hv[30h .. 30h+39]
            #pragma unroll
            for (int i = 0; i < 20; ++i) {
                unsigned int u = *(const unsigned int*)(ha + tid * 74 + h * 30 + 2 * i);
                hw[2 * i]     = __uint_as_float(u << 16);
                hw[2 * i + 1] = __uint_as_float(u & 0xffff0000u);
            }
            #pragma unroll 1
            for (int c = 0; c < 8; ++c) {
                int fc = f * 8 + c;
                float w1r[12], w2r[12];   // wave-uniform -> SGPRs
                #pragma unroll
                for (int j = 0; j < 12; ++j) {
                    w1r[j] = c1w[fc * 12 + j];
                    w2r[j] = c2w[fc * 12 + j];
                }
                float bc = c1b[fc];
                #pragma unroll
                for (int pl = 0; pl < 15; ++pl) {
                    const int p = h * 15 + pl;     // compile-time after unroll
                    float s = bc;
                    #pragma unroll
                    for (int j = 0; j < 12; ++j)
                        s = fmaf(hw[2 * pl + j], w1r[j], s);
                    float g = gelu_fast(s);
                    #pragma unroll
                    for (int d = 0; d < 10; ++d) {
                        const int j2 = p - 2 * d;  // compile-time bounds
                        if (j2 >= 0 && j2 < 12)
                            u2[d] = fmaf(g, w2r[j2], u2[d]);
                    }
                }
            }
        }
        long px = px0 + tid;
        float xv = x0[px * 5 + f];
        #pragma unroll
        for (int d = 0; d < 10; ++d)
            out[px * 50 + f * 10 + d] = xv + u2[d] * (float)(d + 1) * 0.1f;
    }
}

// ---------------------------------------------------------------------------
extern "C" void kernel_launch(void* const* d_in, const int* in_sizes, int n_in,
                              void* d_out, int out_size, void* d_ws, size_t ws_size,
                              hipStream_t stream) {
    (void)in_sizes; (void)n_in; (void)out_size; (void)ws_size;
    const float* xin    = (const float*)d_in[0];
    const float* params = (const float*)d_in[1];
    const float* in_w   = (const float*)d_in[2];
    const float* in_b   = (const float*)d_in[3];
    const float* fnu_w1 = (const float*)d_in[4];
    const float* fnu_b1 = (const float*)d_in[5];
    const float* fnu_w2 = (const float*)d_in[6];
    const float* fnu_b2 = (const float*)d_in[7];
    const float* fnu_w3 = (const float*)d_in[8];
    const float* fnu_b3 = (const float*)d_in[9];
    const float* fw_y   = (const float*)d_in[10];
    const float* fw_x   = (const float*)d_in[11];
    const float* ff_w0  = (const float*)d_in[12];
    const float* ff_b0  = (const float*)d_in[13];
    const float* ff_w1  = (const float*)d_in[14];
    const float* ff_b1  = (const float*)d_in[15];
    const float* ln_g   = (const float*)d_in[16];
    const float* ln_b   = (const float*)d_in[17];
    const float* fa_w   = (const float*)d_in[18];
    const float* fa_b   = (const float*)d_in[19];
    const float* fb_w   = (const float*)d_in[20];
    const float* fb_b   = (const float*)d_in[21];
    const float* c1_w   = (const float*)d_in[22];
    const float* c1_b   = (const float*)d_in[23];
    const float* c2_w   = (const float*)d_in[24];
    const float* c2_b   = (const float*)d_in[25];
    float* out = (float*)d_out;
    float* ws  = (float*)d_ws;

    // workspace (float offsets), total ~41.0M floats (~164 MB)
    unsigned short* tabBf = (unsigned short*)(ws + 0);        // 131072 sh
    unsigned short* tabYF = tabBf;
    unsigned short* tabXF = tabBf + 32768;
    unsigned short* tabYI = tabBf + 65536;
    unsigned short* tabXI = tabBf + 98304;
    unsigned short* W0T   = (unsigned short*)(ws + 65536);    // 65536 sh
    unsigned short* W1T   = (unsigned short*)(ws + 98304);    // 65536 sh
    unsigned short* Wcat  = (unsigned short*)(ws + 131072);   // 25600 sh
    float* bcat = ws + 143872;                                 // 400
    float* att  = ws + 144272;                                 // 64
    unsigned int* c1p = (unsigned int*)(ws + 144336);          // 240 (unused by heads now)
    unsigned int* c2p = (unsigned int*)(ws + 144576);          // 240 (unused by heads now)
    unsigned short* Hbf = (unsigned short*)(ws + 144816);      // 16.8M sh
    float* WRy = ws + 8533424;   // 1048576 each
    float* WIy = ws + 9582000;
    float* WRx = ws + 10630576;
    float* WIx = ws + 11679152;
    unsigned short* WrTy  = (unsigned short*)(ws + 12727728);  // 1M sh each
    unsigned short* WiTy  = (unsigned short*)(ws + 13252016);
    unsigned short* WinTy = (unsigned short*)(ws + 13776304);
    unsigned short* WrTx  = (unsigned short*)(ws + 14300592);
    unsigned short* WiTx  = (unsigned short*)(ws + 14824880);
    unsigned short* WinTx = (unsigned short*)(ws + 15349168);
    unsigned short* Zy    = (unsigned short*)(ws + 15873456);  // 8.4M sh
    unsigned short* Zx    = (unsigned short*)(ws + 20067760);  // 8.4M sh
    unsigned short* Ry    = (unsigned short*)(ws + 24262064);  // 16.8M sh
    unsigned short* Rx    = (unsigned short*)(ws + 32650672);  // 16.8M sh

    k_prep<<<1128, 256, 0, stream>>>(ff_w0, ff_w1, fa_w, fb_w, fa_b, fb_b,
                                     c1_w, c2_w, tabBf, W0T, W1T, Wcat, bcat, c1p, c2p);
    k_att<<<4, 128, 0, stream>>>(params, fnu_w1, fnu_b1, fnu_w2, fnu_b2, fnu_w3, fnu_b3, att);
    k_embed<<<16384, 256, 0, stream>>>(xin, in_w, in_b, Hbf);

    for (int lay = 0; lay < 4; ++lay) {
        const float* attL = att + lay * 16;
        k_wgen2<<<dim3(64, 4, 2), 256, 0, stream>>>(
            fw_y + (long)lay * 2097152, fw_x + (long)lay * 2097152, attL,
            WRy, WIy, WRx, WIx);
        k_wtr2<<<dim3(256, 2), 256, 0, stream>>>(
            WRy, WIy, WRx, WIx, WrTy, WiTy, WinTy, WrTx, WiTx, WinTx);
        k_tf2<<<dim3(1024, 2), 256, 0, stream>>>(tabYF, tabXF, Hbf, Zy, Zx);
        k_mixm2<<<dim3(4, 256, 2), 256, 0, stream>>>(
            Zy, Zx, WrTy, WiTy, WinTy, WrTx, WiTx, WinTx);
        k_ti2<<<dim3(1024, 2), 256, 0, stream>>>(tabYI, tabXI, Zy, Zx, Ry, Rx);
        k_ffm<<<4096, 256, 0, stream>>>(
            Ry, Rx, W0T + lay * 16384, ff_b0 + lay * 256,
            W1T + lay * 16384, ff_b1 + lay * 64,
            ln_g + lay * 64, ln_b + lay * 64,
            Hbf, (lay == 3) ? 1 : 0);
    }
    k_headm<<<1024, 256, 0, stream>>>(Hbf, xin, Wcat, bcat,
                                      c1_w, c1_b, c2_w, c2_b, out);
}

// Round 4
// 1580.485 us; speedup vs baseline: 1.1428x; 1.0721x over previous
//
#include <hip/hip_runtime.h>
#include <math.h>

// ---------------------------------------------------------------------------
// OmniFluids2D forward on MI355X. bf16 dataflow + MFMA everywhere GEMM-shaped.
// Y/X spectral branches merged into double-width launches. B=4, 256^2, W=64.
// R4: k_headm was latency/occupancy-bound (VALUBusy 59%, Occ 11.6%, VGPR 144).
//     Split f across grid (dim3(1024,5)): 5x blocks, per-mi MFMA accumulation
//     (acc[5] live, not acc[4][5]) -> VGPR < 128, 1 barrier instead of 10.
//     VALU-issue floor measured at ~218 us; this recovers toward it.
// ---------------------------------------------------------------------------

typedef __attribute__((ext_vector_type(8))) short sh8;
typedef __attribute__((ext_vector_type(4))) float f4;

__device__ __forceinline__ float fast_rcp(float x) {
#if defined(__has_builtin)
#if __has_builtin(__builtin_amdgcn_rcpf)
    return __builtin_amdgcn_rcpf(x);
#else
    return 1.0f / x;
#endif
#else
    return 1.0f / x;
#endif
}

__device__ __forceinline__ float gelu_f(float v) {          // exact (att only)
    return 0.5f * v * (1.0f + erff(v * 0.70710678118654752f));
}
__device__ __forceinline__ float gelu_fast(float v) {       // tanh-approx, rcp
    float s = v * (1.5957691216f + 0.0713548162f * v * v);
    float e = __expf(-s);
    return v * fast_rcp(1.0f + e);
}
__device__ __forceinline__ unsigned short f2bf(float x) {
    unsigned int u = __float_as_uint(x);
    u += 0x7fffu + ((u >> 16) & 1u);
    return (unsigned short)(u >> 16);
}
__device__ __forceinline__ float bf2f(unsigned short h) {
    return __uint_as_float(((unsigned int)h) << 16);
}

// ------------------------- prep: trig tables + weight packing ----------------
__global__ void k_prep(const float* __restrict__ ff_w0, const float* __restrict__ ff_w1,
                       const float* __restrict__ fa_w, const float* __restrict__ fb_w,
                       const float* __restrict__ fa_b, const float* __restrict__ fb_b,
                       const float* __restrict__ c1w, const float* __restrict__ c2w,
                       unsigned short* __restrict__ tabBf,
                       unsigned short* __restrict__ W0T, unsigned short* __restrict__ W1T,
                       unsigned short* __restrict__ Wcat, float* __restrict__ bcat,
                       unsigned int* __restrict__ c1p, unsigned int* __restrict__ c2p) {
    int idx = blockIdx.x * 256 + threadIdx.x;
    if (idx < 131072) {
        int t = idx >> 15, r = idx & 32767;
        const double PI = 3.14159265358979323846;
        const double s510 = 1.0 / sqrt(510.0);
        double v = 0.0;
        if (t == 0) {            // TAB_YF [row=2m+c][y]  (128x256)
            int row = r >> 8, y = r & 255;
            int m = row >> 1, c = row & 1;
            double ang = 2.0 * PI * (double)(m * y) / 256.0;
            v = (c == 0 ? cos(ang) : -sin(ang)) / 16.0;
        } else if (t == 1) {     // TAB_XF [row=2k+c][x]  (128x256)
            int row = r >> 8, xx = r & 255;
            int k = row >> 1, c = row & 1;
            if (c == 0) {
                v = 0.0;
                if (xx == 0)   v = s510;
                if (xx == 255) v = (k & 1) ? -s510 : s510;
            } else {
                double ang = PI * (double)(k * xx) / 255.0;
                v = -2.0 * s510 * sin(ang);
            }
        } else if (t == 2) {     // TAB_YI [y][row=2m+c]  (256x128)
            int y = r >> 7, row = r & 127;
            int m = row >> 1, c = row & 1;
            double ang = 2.0 * PI * (double)(m * y) / 256.0;
            if (c == 0) v = (m == 0 ? 1.0 : 2.0 * cos(ang)) / 16.0;
            else        v = (m == 0 ? 0.0 : -2.0 * sin(ang) / 16.0);
        } else {                 // TAB_XI [x][row=2k+c]  (256x128)
            int xx = r >> 7, row = r & 127;
            int k = row >> 1, c = row & 1;
            double ang = PI * (double)(k * xx) / 255.0;
            if (c == 0) v = s510 * (k == 0 ? 1.0 : 2.0 * cos(ang));
            else        v = (k == 0 ? 0.0 : -2.0 * s510 * sin(ang));
        }
        tabBf[idx] = f2bf((float)v);
        return;
    }
    idx -= 131072;
    if (idx < 65536) {
        int l = idx >> 14, rem = idx & 16383;
        int n = rem >> 6, k = rem & 63;
        W0T[idx] = f2bf(ff_w0[l * 16384 + k * 256 + n]);
    } else if (idx < 131072) {
        int j = idx - 65536;
        int l = j >> 14, rem = j & 16383;
        int n = rem >> 8, k = rem & 255;
        W1T[j] = f2bf(ff_w1[l * 16384 + k * 64 + n]);
    } else if (idx < 156672) {
        int j = idx - 131072;
        int f = j / 5120, r2 = j % 5120;
        int n = r2 >> 6, k = r2 & 63;
        float v = 0.0f;
        if (n < 36)      v = fa_w[f * 2304 + k * 36 + n];
        else if (n < 70) v = fb_w[f * 2176 + k * 34 + (n - 36)];
        Wcat[j] = f2bf(v);
    } else if (idx < 157072) {
        int j = idx - 156672;
        int f = j / 80, n = j % 80;
        float v = 0.0f;
        if (n < 36)      v = fa_b[f * 36 + n];
        else if (n < 70) v = fb_b[f * 34 + (n - 36)];
        bcat[j] = v;
    } else if (idx < 157552) {
        int j = idx - 157072;         // 0..479 (kept for workspace layout compat)
        int half = j >= 240;
        int r = j - half * 240;       // r = fc*6 + jj, fc = f*8+c
        int fc = r / 6, jj = r % 6;
        const float* src = half ? c2w : c1w;
        unsigned int u = (unsigned int)f2bf(src[fc * 12 + 2 * jj])
                       | ((unsigned int)f2bf(src[fc * 12 + 2 * jj + 1]) << 16);
        (half ? c2p : c1p)[r] = u;
    }
}

// ------------------------- routing attention (one block per layer) -----------
__global__ void k_att(const float* __restrict__ params,
                      const float* __restrict__ w1, const float* __restrict__ b1,
                      const float* __restrict__ w2, const float* __restrict__ b2,
                      const float* __restrict__ w3, const float* __restrict__ b3,
                      float* __restrict__ att) {
    __shared__ float A1[128], A2[128], LG[4];
    int j = threadIdx.x;   // 128 threads
    int lay = blockIdx.x;
    for (int b = 0; b < 4; ++b) {
        float s = b1[lay * 128 + j];
        for (int p = 0; p < 8; ++p) s += params[b * 8 + p] * w1[(lay * 8 + p) * 128 + j];
        A1[j] = gelu_f(s);
        __syncthreads();
        s = b2[lay * 128 + j];
        for (int q = 0; q < 128; ++q) s += A1[q] * w2[(lay * 128 + q) * 128 + j];
        A2[j] = gelu_f(s);
        __syncthreads();
        if (j < 4) {
            float tacc = b3[lay * 4 + j];
            for (int q = 0; q < 128; ++q) tacc += A2[q] * w3[(lay * 128 + q) * 4 + j];
            LG[j] = tacc * 0.1f;
        }
        __syncthreads();
        if (j == 0) {
            float mx = fmaxf(fmaxf(LG[0], LG[1]), fmaxf(LG[2], LG[3]));
            float e0 = expf(LG[0] - mx), e1 = expf(LG[1] - mx);
            float e2 = expf(LG[2] - mx), e3 = expf(LG[3] - mx);
            float inv = 1.0f / (e0 + e1 + e2 + e3);
            att[lay * 16 + b * 4 + 0] = e0 * inv;
            att[lay * 16 + b * 4 + 1] = e1 * inv;
            att[lay * 16 + b * 4 + 2] = e2 * inv;
            att[lay * 16 + b * 4 + 3] = e3 * inv;
        }
        __syncthreads();
    }
}

// ------------------------- input embedding (bf16 H only) ---------------------
__global__ __launch_bounds__(256) void k_embed(const float* __restrict__ xin,
                        const float* __restrict__ inw, const float* __restrict__ inb,
                        unsigned short* __restrict__ Hb) {
    long gid = (long)blockIdx.x * 256 + threadIdx.x;   // 0..4194303
    long px = gid >> 4;
    int c4 = (int)(gid & 15) * 4;
    int y = (int)(px & 255), xi = (int)((px >> 8) & 255);
    const float* xp = xin + px * 5;
    float v[7];
    v[0] = xp[0]; v[1] = xp[1]; v[2] = xp[2]; v[3] = xp[3]; v[4] = xp[4];
    const float STEP = 6.283185307179586f / 256.0f;
    v[5] = xi * STEP;
    v[6] = y * STEP;
    float r[4];
    #pragma unroll
    for (int c = 0; c < 4; ++c) {
        int ch = c4 + c;
        float s = inb[ch];
        #pragma unroll
        for (int p = 0; p < 7; ++p) s += v[p] * inw[p * 64 + ch];
        r[c] = gelu_fast(s);
    }
    uint2 uu;
    uu.x = (unsigned int)f2bf(r[0]) | ((unsigned int)f2bf(r[1]) << 16);
    uu.y = (unsigned int)f2bf(r[2]) | ((unsigned int)f2bf(r[3]) << 16);
    *(uint2*)(Hb + px * 64 + c4) = uu;
}

// ------------------------- W generation, both branches -----------------------
__global__ __launch_bounds__(256) void k_wgen2(
    const float* __restrict__ fwY, const float* __restrict__ fwX,
    const float* __restrict__ att,
    float* __restrict__ WRy, float* __restrict__ WIy,
    float* __restrict__ WRx, float* __restrict__ WIx) {
    int ii = blockIdx.x, b = blockIdx.y, z = blockIdx.z;
    const float* fw = z ? fwX : fwY;
    float* WRo = z ? WRx : WRy;
    float* WIo = z ? WIx : WIy;
    int tid = threadIdx.x;
    float av[4];
    av[0] = att[b * 4 + 0]; av[1] = att[b * 4 + 1];
    av[2] = att[b * 4 + 2]; av[3] = att[b * 4 + 3];
    float acc[32];
    #pragma unroll
    for (int j = 0; j < 32; ++j) acc[j] = 0.0f;
    const float* base = fw + (long)ii * 8192;
    for (int k = 0; k < 4; ++k) {
        const float* p = base + (long)k * 524288;
        float a = av[k];
        #pragma unroll
        for (int j = 0; j < 32; ++j) acc[j] += a * p[tid + j * 256];
    }
    __shared__ float ldsR[64 * 65], ldsI[64 * 65];
    #pragma unroll
    for (int j = 0; j < 32; ++j) {
        int l = tid + j * 256;                 // l over [o][m][c]
        int o = l >> 7, m = (l >> 1) & 63, c = l & 1;
        (c ? ldsI : ldsR)[o * 65 + m] = acc[j];
    }
    __syncthreads();
    long ob = (long)b * 262144 + (long)ii * 64;
    for (int w = tid; w < 4096; w += 256) {
        int m = w >> 6, o = w & 63;
        WRo[ob + (long)m * 4096 + o] = ldsR[o * 65 + m];
        WIo[ob + (long)m * 4096 + o] = ldsI[o * 65 + m];
    }
}

// ------------------------- W transpose to bf16, both branches ----------------
__global__ __launch_bounds__(256) void k_wtr2(
    const float* __restrict__ WRy, const float* __restrict__ WIy,
    const float* __restrict__ WRx, const float* __restrict__ WIx,
    unsigned short* __restrict__ WrTy, unsigned short* __restrict__ WiTy,
    unsigned short* __restrict__ WinTy,
    unsigned short* __restrict__ WrTx, unsigned short* __restrict__ WiTx,
    unsigned short* __restrict__ WinTx) {
    int z = blockIdx.y;
    const float* WR = z ? WRx : WRy;
    const float* WI = z ? WIx : WIy;
    unsigned short* WrT  = z ? WrTx  : WrTy;
    unsigned short* WiT  = z ? WiTx  : WiTy;
    unsigned short* WinT = z ? WinTx : WinTy;
    __shared__ float lR[64 * 65], lI[64 * 65];
    long base = (long)blockIdx.x * 4096;    // (b*64+m)
    int tid = threadIdx.x;
    #pragma unroll
    for (int it = 0; it < 16; ++it) {
        int l = it * 256 + tid;
        int i = l >> 6, o = l & 63;
        lR[i * 65 + o] = WR[base + l];
        lI[i * 65 + o] = WI[base + l];
    }
    __syncthreads();
    #pragma unroll
    for (int it = 0; it < 16; ++it) {
        int l = it * 256 + tid;
        int o = l >> 6, i = l & 63;
        float rr = lR[i * 65 + o], im = lI[i * 65 + o];
        WrT[base + l]  = f2bf(rr);
        WiT[base + l]  = f2bf(im);
        WinT[base + l] = f2bf(-im);
    }
}

// ------------------------- B^T staging: global rows -> lds[n][k] -------------
__device__ __forceinline__ void stage_bt(unsigned short* lds, int pitch,
    const unsigned short* src, int rowStride, int K, int tid)
{
    int pairs = K >> 1;
    int tasks = pairs * 8;
    for (int idx = tid; idx < tasks; idx += 256) {
        int p = idx & (pairs - 1);
        int cg = idx / pairs;
        const unsigned short* s0 = src + (long)(2 * p) * rowStride + cg * 8;
        sh8 r0 = *(const sh8*)s0;
        sh8 r1 = *(const sh8*)(s0 + rowStride);
        unsigned short* dbase = lds + cg * 8 * pitch + 2 * p;
        #pragma unroll
        for (int j = 0; j < 8; ++j) {
            unsigned int u = (unsigned int)(unsigned short)r0[j]
                           | ((unsigned int)(unsigned short)r1[j] << 16);
            *(unsigned int*)(dbase + j * pitch) = u;
        }
    }
}

// ------------------------- MFMA forward transform, both branches -------------
__global__ __launch_bounds__(256) void k_tf2(
    const unsigned short* __restrict__ tabY, const unsigned short* __restrict__ tabX,
    const unsigned short* __restrict__ Hb,
    unsigned short* __restrict__ Zy, unsigned short* __restrict__ Zx)
{
    __shared__ __align__(16) unsigned short ldsB[64 * 272];
    int g = blockIdx.x, br = blockIdx.y;
    int b = g >> 8, s = g & 255;
    const unsigned short* tab = br ? tabX : tabY;
    unsigned short* Zo = br ? Zx : Zy;
    long sLo = br ? 64L : 16384L;
    int rowStride = br ? 16384 : 64;
    int tid = threadIdx.x;
    const unsigned short* src = Hb + (long)b * 4194304 + (long)s * sLo;
    stage_bt(ldsB, 272, src, rowStride, 256, tid);
    __syncthreads();
    int w = tid >> 6, lane = tid & 63, q = lane >> 4, ln = lane & 15;
    f4 acc[2][4];
    #pragma unroll
    for (int mi = 0; mi < 2; ++mi)
        #pragma unroll
        for (int ni = 0; ni < 4; ++ni) acc[mi][ni] = (f4){0.f, 0.f, 0.f, 0.f};
    for (int kc = 0; kc < 256; kc += 32) {
        sh8 a[2], bf[4];
        #pragma unroll
        for (int mi = 0; mi < 2; ++mi)
            a[mi] = *(const sh8*)(tab + (w * 32 + mi * 16 + ln) * 256 + kc + q * 8);
        #pragma unroll
        for (int ni = 0; ni < 4; ++ni)
            bf[ni] = *(const sh8*)(ldsB + (ni * 16 + ln) * 272 + kc + q * 8);
        #pragma unroll
        for (int mi = 0; mi < 2; ++mi)
            #pragma unroll
            for (int ni = 0; ni < 4; ++ni)
                acc[mi][ni] = __builtin_amdgcn_mfma_f32_16x16x32_bf16(
                    a[mi], bf[ni], acc[mi][ni], 0, 0, 0);
    }
    long zB = (long)b * 2097152 + (long)s * 8192;
    #pragma unroll
    for (int mi = 0; mi < 2; ++mi)
        #pragma unroll
        for (int ni = 0; ni < 4; ++ni)
            #pragma unroll
            for (int reg = 0; reg < 4; ++reg) {
                int r = w * 32 + mi * 16 + q * 4 + reg;
                Zo[zB + r * 64 + ni * 16 + ln] = f2bf(acc[mi][ni][reg]);
            }
}

// ------------------------- MFMA complex mode-mix, both branches --------------
__global__ __launch_bounds__(256) void k_mixm2(
    unsigned short* Zy, unsigned short* Zx,
    const unsigned short* __restrict__ WrTy, const unsigned short* __restrict__ WiTy,
    const unsigned short* __restrict__ WinTy,
    const unsigned short* __restrict__ WrTx, const unsigned short* __restrict__ WiTx,
    const unsigned short* __restrict__ WinTx)
{
    int xt = blockIdx.x, g = blockIdx.y, z = blockIdx.z;
    unsigned short* Z = z ? Zx : Zy;
    const unsigned short* WrT  = z ? WrTx  : WrTy;
    const unsigned short* WiT  = z ? WiTx  : WiTy;
    const unsigned short* WinT = z ? WinTx : WinTy;
    int b = g >> 6, m = g & 63;
    int tid = threadIdx.x, w = tid >> 6, lane = tid & 63, q = lane >> 4, ln = lane & 15;
    long zB = (long)b * 2097152 + (long)m * 128;
    long wB = (long)b * 262144 + (long)m * 4096;
    int s0 = xt * 64 + w * 16;
    f4 aR[4], aI[4];
    #pragma unroll
    for (int nt = 0; nt < 4; ++nt) { aR[nt] = (f4){0.f,0.f,0.f,0.f}; aI[nt] = (f4){0.f,0.f,0.f,0.f}; }
    for (int kc = 0; kc < 64; kc += 32) {
        sh8 zr = *(const sh8*)(Z + zB + (long)(s0 + ln) * 8192 + kc + q * 8);
        sh8 zi = *(const sh8*)(Z + zB + (long)(s0 + ln) * 8192 + 64 + kc + q * 8);
        #pragma unroll
        for (int nt = 0; nt < 4; ++nt) {
            int o = nt * 16 + ln;
            sh8 wr = *(const sh8*)(WrT + wB + o * 64 + kc + q * 8);
            sh8 wi = *(const sh8*)(WiT + wB + o * 64 + kc + q * 8);
            sh8 wn = *(const sh8*)(WinT + wB + o * 64 + kc + q * 8);
            aR[nt] = __builtin_amdgcn_mfma_f32_16x16x32_bf16(zr, wr, aR[nt], 0, 0, 0);
            aR[nt] = __builtin_amdgcn_mfma_f32_16x16x32_bf16(zi, wn, aR[nt], 0, 0, 0);
            aI[nt] = __builtin_amdgcn_mfma_f32_16x16x32_bf16(zr, wi, aI[nt], 0, 0, 0);
            aI[nt] = __builtin_amdgcn_mfma_f32_16x16x32_bf16(zi, wr, aI[nt], 0, 0, 0);
        }
    }
    #pragma unroll
    for (int nt = 0; nt < 4; ++nt)
        #pragma unroll
        for (int reg = 0; reg < 4; ++reg) {
            int s = s0 + q * 4 + reg;
            long a = zB + (long)s * 8192 + nt * 16 + ln;
            Z[a]      = f2bf(aR[nt][reg]);
            Z[a + 64] = f2bf(aI[nt][reg]);
        }
}

// ------------------------- MFMA inverse transform, both branches -------------
// z=0: Ry[b][x][y][o] from Zy ; z=1: Rx[b][y][x][o] from Zx (both contiguous).
__global__ __launch_bounds__(256) void k_ti2(
    const unsigned short* __restrict__ tabY, const unsigned short* __restrict__ tabX,
    const unsigned short* __restrict__ Zy, const unsigned short* __restrict__ Zx,
    unsigned short* __restrict__ Ry, unsigned short* __restrict__ Rx)
{
    __shared__ __align__(16) unsigned short ldsB[64 * 144];
    int g = blockIdx.x, br = blockIdx.y;
    int b = g >> 8, s = g & 255;
    const unsigned short* tab = br ? tabX : tabY;
    const unsigned short* Zl  = br ? Zx : Zy;
    unsigned short* Ro = br ? Rx : Ry;
    int tid = threadIdx.x;
    const unsigned short* src = Zl + (long)b * 2097152 + (long)s * 8192;
    stage_bt(ldsB, 144, src, 64, 128, tid);
    __syncthreads();
    int w = tid >> 6, lane = tid & 63, q = lane >> 4, ln = lane & 15;
    f4 acc[4][4];
    #pragma unroll
    for (int mi = 0; mi < 4; ++mi)
        #pragma unroll
        for (int ni = 0; ni < 4; ++ni) acc[mi][ni] = (f4){0.f, 0.f, 0.f, 0.f};
    for (int kc = 0; kc < 128; kc += 32) {
        sh8 a[4], bf[4];
        #pragma unroll
        for (int mi = 0; mi < 4; ++mi)
            a[mi] = *(const sh8*)(tab + (w * 64 + mi * 16 + ln) * 128 + kc + q * 8);
        #pragma unroll
        for (int ni = 0; ni < 4; ++ni)
            bf[ni] = *(const sh8*)(ldsB + (ni * 16 + ln) * 144 + kc + q * 8);
        #pragma unroll
        for (int mi = 0; mi < 4; ++mi)
            #pragma unroll
            for (int ni = 0; ni < 4; ++ni)
                acc[mi][ni] = __builtin_amdgcn_mfma_f32_16x16x32_bf16(
                    a[mi], bf[ni], acc[mi][ni], 0, 0, 0);
    }
    long rB = (long)b * 4194304 + (long)s * 16384;
    #pragma unroll
    for (int mi = 0; mi < 4; ++mi)
        #pragma unroll
        for (int ni = 0; ni < 4; ++ni)
            #pragma unroll
            for (int reg = 0; reg < 4; ++reg) {
                int r2 = w * 64 + mi * 16 + q * 4 + reg;
                Ro[rB + (long)r2 * 64 + ni * 16 + ln] = f2bf(acc[mi][ni][reg]);
            }
}

// ------------------------- MFMA fused FeedForward + LN -----------------------
// A = bf16(Ry + Rx) built in registers; residual stream in bf16 (Hb).
__global__ __launch_bounds__(256) void k_ffm(
    const unsigned short* __restrict__ Ry, const unsigned short* __restrict__ Rx,
    const unsigned short* __restrict__ W0T, const float* __restrict__ b0,
    const unsigned short* __restrict__ W1T, const float* __restrict__ b1,
    const float* __restrict__ g1, const float* __restrict__ be1,
    unsigned short* __restrict__ Hb, int last)
{
    __shared__ __align__(16) unsigned short T[64 * 264];
    int m0 = blockIdx.x * 64;
    int tid = threadIdx.x, w = tid >> 6, lane = tid & 63, q = lane >> 4, ln = lane & 15;
    int row = m0 + w * 16 + ln;
    int bb = row >> 16, xx2 = (row >> 8) & 255, yy = row & 255;
    const unsigned short* ryp = Ry + (long)row * 64;
    const unsigned short* rxp = Rx + (long)bb * 4194304 + (long)yy * 16384 + xx2 * 64;
    // phase 1: T = relu((Ry+Rx) @ W0 + b0), rows w*16..+15, N=256
    {
        f4 acc1[16];
        #pragma unroll
        for (int nt = 0; nt < 16; ++nt) acc1[nt] = (f4){0.f, 0.f, 0.f, 0.f};
        for (int kc = 0; kc < 64; kc += 32) {
            sh8 ry = *(const sh8*)(ryp + kc + q * 8);
            sh8 rx = *(const sh8*)(rxp + kc + q * 8);
            sh8 a;
            #pragma unroll
            for (int j = 0; j < 8; ++j)
                a[j] = (short)f2bf(bf2f((unsigned short)ry[j]) + bf2f((unsigned short)rx[j]));
            #pragma unroll
            for (int nt = 0; nt < 16; ++nt) {
                sh8 bf = *(const sh8*)(W0T + (nt * 16 + ln) * 64 + kc + q * 8);
                acc1[nt] = __builtin_amdgcn_mfma_f32_16x16x32_bf16(a, bf, acc1[nt], 0, 0, 0);
            }
        }
        #pragma unroll
        for (int nt = 0; nt < 16; ++nt) {
            int n = nt * 16 + ln;
            float bias = b0[n];
            #pragma unroll
            for (int reg = 0; reg < 4; ++reg) {
                int m = w * 16 + q * 4 + reg;
                T[m * 264 + n] = f2bf(fmaxf(acc1[nt][reg] + bias, 0.0f));
            }
        }
    }
    // phase 2 (intra-wave LDS dep): t = T @ W1 + b1, then LN + residual
    f4 acc2[4];
    #pragma unroll
    for (int nt = 0; nt < 4; ++nt) acc2[nt] = (f4){0.f, 0.f, 0.f, 0.f};
    for (int kc = 0; kc < 256; kc += 32) {
        sh8 a = *(const sh8*)(T + (w * 16 + ln) * 264 + kc + q * 8);
        #pragma unroll
        for (int nt = 0; nt < 4; ++nt) {
            sh8 bf = *(const sh8*)(W1T + (nt * 16 + ln) * 256 + kc + q * 8);
            acc2[nt] = __builtin_amdgcn_mfma_f32_16x16x32_bf16(a, bf, acc2[nt], 0, 0, 0);
        }
    }
    float bia[4], gg[4], bb4[4];
    #pragma unroll
    for (int nt = 0; nt < 4; ++nt) {
        int n = nt * 16 + ln;
        bia[nt] = b1[n]; gg[nt] = g1[n]; bb4[nt] = be1[n];
    }
    #pragma unroll
    for (int reg = 0; reg < 4; ++reg) {
        float t[4];
        float s = 0.f, qs = 0.f;
        #pragma unroll
        for (int nt = 0; nt < 4; ++nt) {
            t[nt] = acc2[nt][reg] + bia[nt];
            s += t[nt]; qs += t[nt] * t[nt];
        }
        #pragma unroll
        for (int d = 1; d < 16; d <<= 1) {
            s  += __shfl_xor(s, d, 64);
            qs += __shfl_xor(qs, d, 64);
        }
        float mean = s * (1.0f / 64.0f);
        float var  = qs * (1.0f / 64.0f) - mean * mean;
        float inv  = rsqrtf(var + 1e-5f);
        int m = w * 16 + q * 4 + reg;
        long base = (long)(m0 + m) * 64;
        #pragma unroll
        for (int nt = 0; nt < 4; ++nt) {
            int n = nt * 16 + ln;
            float v = (t[nt] - mean) * inv * gg[nt] + bb4[nt];
            float hv;
            if (last) hv = gelu_fast(v);
            else      hv = bf2f(Hb[base + n]) + v;
            Hb[base + n] = f2bf(hv);
        }
    }
}

// ------------------------- output heads (MFMA ha + fp32 conv) ----------------
// One f per block (blockIdx.y): 5120 blocks, per-mi MFMA accumulation keeps
// VGPR < 128, single barrier.
__global__ __launch_bounds__(256) void k_headm(
    const unsigned short* __restrict__ Hb, const float* __restrict__ x0,
    const unsigned short* __restrict__ Wcat, const float* __restrict__ bcat,
    const float* __restrict__ c1w, const float* __restrict__ c1b,
    const float* __restrict__ c2w, const float* __restrict__ c2b,
    float* __restrict__ out)
{
    __shared__ unsigned short ha[256 * 74];   // [px][j], pitch 74 (gcd(37,32)=1)
    int tid = threadIdx.x;
    int f = blockIdx.y;
    long px0 = (long)blockIdx.x * 256;
    int w = tid >> 6, lane = tid & 63, q = lane >> 4, ln = lane & 15;

    // ha-GEMM, one mi (16 rows) at a time: acc[5] live, not acc[4][5]
    #pragma unroll
    for (int mi = 0; mi < 4; ++mi) {
        f4 acc[5];
        #pragma unroll
        for (int nt = 0; nt < 5; ++nt) acc[nt] = (f4){0.f, 0.f, 0.f, 0.f};
        #pragma unroll
        for (int kc = 0; kc < 2; ++kc) {
            sh8 a = *(const sh8*)(Hb + (px0 + w * 64 + mi * 16 + ln) * 64
                                   + kc * 32 + q * 8);
            #pragma unroll
            for (int nt = 0; nt < 5; ++nt) {
                sh8 bf = *(const sh8*)(Wcat + f * 5120 + (nt * 16 + ln) * 64
                                        + kc * 32 + q * 8);
                acc[nt] = __builtin_amdgcn_mfma_f32_16x16x32_bf16(a, bf, acc[nt], 0, 0, 0);
            }
        }
        #pragma unroll
        for (int nt = 0; nt < 5; ++nt) {
            int n = nt * 16 + ln;
            if (n < 70) {
                float bias = bcat[f * 80 + n];
                #pragma unroll
                for (int reg = 0; reg < 4; ++reg) {
                    int m = w * 64 + mi * 16 + q * 4 + reg;
                    ha[m * 74 + n] = f2bf(gelu_fast(acc[nt][reg] + bias));
                }
            }
        }
    }
    __syncthreads();

    // conv phase: one pixel per thread, fp32 FMA.
    // - conv2 scattered immediately after each gelu: no u1[30] live array
    // - hv window processed in two 40-float halves: peak live ~70 regs
    float u2[10];
    float b2v = c2b[f];
    #pragma unroll
    for (int d = 0; d < 10; ++d) u2[d] = b2v;
    #pragma unroll
    for (int h = 0; h < 2; ++h) {
        float hw[40];   // hv[30h .. 30h+39]
        #pragma unroll
        for (int i = 0; i < 20; ++i) {
            unsigned int u = *(const unsigned int*)(ha + tid * 74 + h * 30 + 2 * i);
            hw[2 * i]     = __uint_as_float(u << 16);
            hw[2 * i + 1] = __uint_as_float(u & 0xffff0000u);
        }
        #pragma unroll 1
        for (int c = 0; c < 8; ++c) {
            int fc = f * 8 + c;
            float w1r[12], w2r[12];   // wave-uniform -> SGPRs
            #pragma unroll
            for (int j = 0; j < 12; ++j) {
                w1r[j] = c1w[fc * 12 + j];
                w2r[j] = c2w[fc * 12 + j];
            }
            float bc = c1b[fc];
            #pragma unroll
            for (int pl = 0; pl < 15; ++pl) {
                const int p = h * 15 + pl;     // compile-time after unroll
                float s = bc;
                #pragma unroll
                for (int j = 0; j < 12; ++j)
                    s = fmaf(hw[2 * pl + j], w1r[j], s);
                float g = gelu_fast(s);
                #pragma unroll
                for (int d = 0; d < 10; ++d) {
                    const int j2 = p - 2 * d;  // compile-time bounds
                    if (j2 >= 0 && j2 < 12)
                        u2[d] = fmaf(g, w2r[j2], u2[d]);
                }
            }
        }
    }
    long px = px0 + tid;
    float xv = x0[px * 5 + f];
    #pragma unroll
    for (int d = 0; d < 10; ++d)
        out[px * 50 + f * 10 + d] = xv + u2[d] * (float)(d + 1) * 0.1f;
}

// ---------------------------------------------------------------------------
extern "C" void kernel_launch(void* const* d_in, const int* in_sizes, int n_in,
                              void* d_out, int out_size, void* d_ws, size_t ws_size,
                              hipStream_t stream) {
    (void)in_sizes; (void)n_in; (void)out_size; (void)ws_size;
    const float* xin    = (const float*)d_in[0];
    const float* params = (const float*)d_in[1];
    const float* in_w   = (const float*)d_in[2];
    const float* in_b   = (const float*)d_in[3];
    const float* fnu_w1 = (const float*)d_in[4];
    const float* fnu_b1 = (const float*)d_in[5];
    const float* fnu_w2 = (const float*)d_in[6];
    const float* fnu_b2 = (const float*)d_in[7];
    const float* fnu_w3 = (const float*)d_in[8];
    const float* fnu_b3 = (const float*)d_in[9];
    const float* fw_y   = (const float*)d_in[10];
    const float* fw_x   = (const float*)d_in[11];
    const float* ff_w0  = (const float*)d_in[12];
    const float* ff_b0  = (const float*)d_in[13];
    const float* ff_w1  = (const float*)d_in[14];
    const float* ff_b1  = (const float*)d_in[15];
    const float* ln_g   = (const float*)d_in[16];
    const float* ln_b   = (const float*)d_in[17];
    const float* fa_w   = (const float*)d_in[18];
    const float* fa_b   = (const float*)d_in[19];
    const float* fb_w   = (const float*)d_in[20];
    const float* fb_b   = (const float*)d_in[21];
    const float* c1_w   = (const float*)d_in[22];
    const float* c1_b   = (const float*)d_in[23];
    const float* c2_w   = (const float*)d_in[24];
    const float* c2_b   = (const float*)d_in[25];
    float* out = (float*)d_out;
    float* ws  = (float*)d_ws;

    // workspace (float offsets), total ~41.0M floats (~164 MB)
    unsigned short* tabBf = (unsigned short*)(ws + 0);        // 131072 sh
    unsigned short* tabYF = tabBf;
    unsigned short* tabXF = tabBf + 32768;
    unsigned short* tabYI = tabBf + 65536;
    unsigned short* tabXI = tabBf + 98304;
    unsigned short* W0T   = (unsigned short*)(ws + 65536);    // 65536 sh
    unsigned short* W1T   = (unsigned short*)(ws + 98304);    // 65536 sh
    unsigned short* Wcat  = (unsigned short*)(ws + 131072);   // 25600 sh
    float* bcat = ws + 143872;                                 // 400
    float* att  = ws + 144272;                                 // 64
    unsigned int* c1p = (unsigned int*)(ws + 144336);          // 240 (unused by heads now)
    unsigned int* c2p = (unsigned int*)(ws + 144576);          // 240 (unused by heads now)
    unsigned short* Hbf = (unsigned short*)(ws + 144816);      // 16.8M sh
    float* WRy = ws + 8533424;   // 1048576 each
    float* WIy = ws + 9582000;
    float* WRx = ws + 10630576;
    float* WIx = ws + 11679152;
    unsigned short* WrTy  = (unsigned short*)(ws + 12727728);  // 1M sh each
    unsigned short* WiTy  = (unsigned short*)(ws + 13252016);
    unsigned short* WinTy = (unsigned short*)(ws + 13776304);
    unsigned short* WrTx  = (unsigned short*)(ws + 14300592);
    unsigned short* WiTx  = (unsigned short*)(ws + 14824880);
    unsigned short* WinTx = (unsigned short*)(ws + 15349168);
    unsigned short* Zy    = (unsigned short*)(ws + 15873456);  // 8.4M sh
    unsigned short* Zx    = (unsigned short*)(ws + 20067760);  // 8.4M sh
    unsigned short* Ry    = (unsigned short*)(ws + 24262064);  // 16.8M sh
    unsigned short* Rx    = (unsigned short*)(ws + 32650672);  // 16.8M sh

    k_prep<<<1128, 256, 0, stream>>>(ff_w0, ff_w1, fa_w, fb_w, fa_b, fb_b,
                                     c1_w, c2_w, tabBf, W0T, W1T, Wcat, bcat, c1p, c2p);
    k_att<<<4, 128, 0, stream>>>(params, fnu_w1, fnu_b1, fnu_w2, fnu_b2, fnu_w3, fnu_b3, att);
    k_embed<<<16384, 256, 0, stream>>>(xin, in_w, in_b, Hbf);

    for (int lay = 0; lay < 4; ++lay) {
        const float* attL = att + lay * 16;
        k_wgen2<<<dim3(64, 4, 2), 256, 0, stream>>>(
            fw_y + (long)lay * 2097152, fw_x + (long)lay * 2097152, attL,
            WRy, WIy, WRx, WIx);
        k_wtr2<<<dim3(256, 2), 256, 0, stream>>>(
            WRy, WIy, WRx, WIx, WrTy, WiTy, WinTy, WrTx, WiTx, WinTx);
        k_tf2<<<dim3(1024, 2), 256, 0, stream>>>(tabYF, tabXF, Hbf, Zy, Zx);
        k_mixm2<<<dim3(4, 256, 2), 256, 0, stream>>>(
            Zy, Zx, WrTy, WiTy, WinTy, WrTx, WiTx, WinTx);
        k_ti2<<<dim3(1024, 2), 256, 0, stream>>>(tabYI, tabXI, Zy, Zx, Ry, Rx);
        k_ffm<<<4096, 256, 0, stream>>>(
            Ry, Rx, W0T + lay * 16384, ff_b0 + lay * 256,
            W1T + lay * 16384, ff_b1 + lay * 64,
            ln_g + lay * 64, ln_b + lay * 64,
            Hbf, (lay == 3) ? 1 : 0);
    }
    k_headm<<<dim3(1024, 5), 256, 0, stream>>>(Hbf, xin, Wcat, bcat,
                                               c1_w, c1_b, c2_w, c2_b, out);
}